// Round 3
// baseline (265.141 us; speedup 1.0000x reference)
//
#include <hip/hip_runtime.h>
#include <cmath>

typedef unsigned short u16;
typedef unsigned int   u32;
typedef __attribute__((ext_vector_type(8))) __bf16 bf16x8;
typedef __attribute__((ext_vector_type(2))) __bf16 bf16x2;
typedef __attribute__((ext_vector_type(4))) float  f32x4;
typedef __attribute__((ext_vector_type(2))) unsigned int u32x2;

constexpr int BB = 2, SEQ = 2048, CH = 1024, NH = 16, DH = 64;

__device__ inline u16 f2bf(float f) {            // RNE fp32 -> bf16
    u32 u = __builtin_bit_cast(u32, f);
    u += 0x7FFF + ((u >> 16) & 1);
    return (u16)(u >> 16);
}
__device__ inline float bf2f(u16 b) { return __builtin_bit_cast(float, (u32)b << 16); }
__device__ inline u32 pkbf(float a, float b) {   // pack two RNE bf16 into u32
#if __has_builtin(__builtin_amdgcn_cvt_pk_bf16_f32)
    bf16x2 r = __builtin_amdgcn_cvt_pk_bf16_f32(a, b);
    return __builtin_bit_cast(u32, r);
#else
    return (u32)f2bf(a) | ((u32)f2bf(b) << 16);
#endif
}
__device__ inline float fexp2(float x) {
#if __has_builtin(__builtin_amdgcn_exp2f)
    return __builtin_amdgcn_exp2f(x);
#else
    return exp2f(x);
#endif
}

// permlane swaps (gfx950). P32: a'=[a0,a1,b0,b1] b'=[a2,a3,b2,b3] (16-lane rows)
// P16: a'=[a0,b0,a2,b2] b'=[a1,b1,a3,b3]
__device__ inline void pl32swap(u32& a, u32& b) {
#if __has_builtin(__builtin_amdgcn_permlane32_swap)
    u32x2 r = __builtin_amdgcn_permlane32_swap(a, b, false, false);
    a = r.x; b = r.y;
#else
    const int ln = threadIdx.x & 63;
    u32 ax = (u32)__shfl_xor((int)a, 32), bx = (u32)__shfl_xor((int)b, 32);
    u32 na = (ln & 32) ? bx : a;
    u32 nb = (ln & 32) ? b : ax;
    a = na; b = nb;
#endif
}
__device__ inline void pl16swap(u32& a, u32& b) {
#if __has_builtin(__builtin_amdgcn_permlane16_swap)
    u32x2 r = __builtin_amdgcn_permlane16_swap(a, b, false, false);
    a = r.x; b = r.y;
#else
    const int ln = threadIdx.x & 63;
    u32 ax = (u32)__shfl_xor((int)a, 16), bx = (u32)__shfl_xor((int)b, 16);
    u32 na = (ln & 16) ? bx : a;
    u32 nb = (ln & 16) ? b : ax;
    a = na; b = nb;
#endif
}

__device__ inline void gld_lds16(const void* g, void* l) {
    __builtin_amdgcn_global_load_lds((const __attribute__((address_space(1))) void*)g,
                                     (__attribute__((address_space(3))) void*)l, 16, 0, 0);
}
__device__ inline f32x4 mfma16(bf16x8 a, bf16x8 b, f32x4 c) {
    return __builtin_amdgcn_mfma_f32_16x16x32_bf16(a, b, c, 0, 0, 0);
}
__device__ inline bf16x8 ld_frag(const u16* p) {
    return __builtin_bit_cast(bf16x8, *(const uint4*)p);
}

// ---------------------------------------------------------------------------
// fp32 -> bf16 conversion for x, qkv_w, proj_w + RoPE sin/cos table gen.
// ---------------------------------------------------------------------------
__global__ __launch_bounds__(256) void convert_kernel(const float* __restrict__ x,
                                                      const float* __restrict__ wq,
                                                      const float* __restrict__ wp,
                                                      u16* __restrict__ xb,
                                                      u16* __restrict__ wqb,
                                                      u16* __restrict__ wpb,
                                                      float2* __restrict__ tabq,
                                                      float2* __restrict__ tabk) {
    const int q = blockIdx.x * 256 + threadIdx.x;   // quad index
    if (q >= 2097152) {                             // table-gen tail: 1024 threads
        const int idx = q - 2097152;
        if (idx < 1024) {
            const int p = idx >> 4, i = idx & 15;
            const float f = exp2f(-(float)i * 0.41524101186092f);  // log2(100)/16
            float s, c;
            sincosf((float)p * f, &s, &c);
            tabk[idx] = make_float2(c, s);
            tabq[idx] = make_float2(c * 0.18033688011112042f,
                                    s * 0.18033688011112042f);
        }
        return;
    }
    const float* src; u16* dst; int idx;
    if (q < 1048576)            { src = x;  dst = xb;  idx = q; }
    else if (q < 1048576+786432){ src = wq; dst = wqb; idx = q - 1048576; }
    else                        { src = wp; dst = wpb; idx = q - 1048576 - 786432; }
    float4 v = *(const float4*)(src + (size_t)idx * 4);
    ushort4 o; o.x = f2bf(v.x); o.y = f2bf(v.y); o.z = f2bf(v.z); o.w = f2bf(v.w);
    *(ushort4*)(dst + (size_t)idx * 4) = o;
}

// ---------------------------------------------------------------------------
// Fused QKV GEMM + RoPE + head-major repack, double-buffered staging,
// LDS-transpose epilogue (all three outputs written as coalesced 16B chunks).
// ---------------------------------------------------------------------------
__global__ __launch_bounds__(256) void gemm_qkv_rope(const u16* __restrict__ A,
                                                     const u16* __restrict__ Bw,
                                                     const int* __restrict__ pos,
                                                     const float2* __restrict__ tabq,
                                                     const float2* __restrict__ tabk,
                                                     u16* __restrict__ Qb,
                                                     u16* __restrict__ Kb,
                                                     u16* __restrict__ Vt) {
    __shared__ u16 smem[18432];   // dbuf staging [0,16384); epilogue T = 4 x 4608
    const int t = threadIdx.x, lane = t & 63, w = t >> 6;
    const int l15 = lane & 15, quad = lane >> 4;
    const int wm = w >> 1, wn = w & 1;
    const int m0 = blockIdx.y * 128, n0 = blockIdx.x * 128;
    const int K = CH;

    const int row0 = t >> 2, v0 = t & 3;
    const int gi0 = (v0 - (row0 >> 1)) & 3;
    const int row1 = row0 + 64;
    const int gi1 = (v0 - (row1 >> 1)) & 3;

    const u16* A0 = A  + (size_t)(m0 + row0) * K + gi0 * 8;
    const u16* A1 = A  + (size_t)(m0 + row1) * K + gi1 * 8;
    const u16* B0 = Bw + (size_t)(n0 + row0) * K + gi0 * 8;
    const u16* B1 = Bw + (size_t)(n0 + row1) * K + gi1 * 8;

    gld_lds16(A0, smem + t * 8);
    gld_lds16(A1, smem + 2048 + t * 8);
    gld_lds16(B0, smem + 8192 + t * 8);
    gld_lds16(B1, smem + 10240 + t * 8);

    f32x4 acc[4][4] = {};
    for (int kt = 0; kt < K / 32; ++kt) {
        __syncthreads();          // drains own prefetch (vmcnt 0) + block sync
        const int cur = (kt & 1) * 4096;
        if (kt + 1 < K / 32) {
            const int off = (kt + 1) * 32;
            const int nxt = ((kt + 1) & 1) * 4096;
            gld_lds16(A0 + off, smem + nxt + t * 8);
            gld_lds16(A1 + off, smem + nxt + 2048 + t * 8);
            gld_lds16(B0 + off, smem + 8192 + nxt + t * 8);
            gld_lds16(B1 + off, smem + 8192 + nxt + 2048 + t * 8);
        }
        const u16* as = smem + cur;
        const u16* bs = smem + 8192 + cur;
        bf16x8 af[4], bfv[4];
#pragma unroll
        for (int mi = 0; mi < 4; ++mi) {
            const int r = wm * 64 + mi * 16 + l15;
            af[mi] = ld_frag(as + (r * 4 + ((quad + (r >> 1)) & 3)) * 8);
        }
#pragma unroll
        for (int nj = 0; nj < 4; ++nj) {
            const int r = wn * 64 + nj * 16 + l15;
            bfv[nj] = ld_frag(bs + (r * 4 + ((quad + (r >> 1)) & 3)) * 8);
        }
#pragma unroll
        for (int mi = 0; mi < 4; ++mi)
#pragma unroll
            for (int nj = 0; nj < 4; ++nj)
                acc[mi][nj] = mfma16(af[mi], bfv[nj], acc[mi][nj]);
    }

    const int reg = n0 >> 10;                      // 0=q, 1=k, 2=v (block-uniform)
    const int h   = ((n0 & 1023) >> 6) + wn;       // wave's head
    __syncthreads();                               // staging fully consumed
    u16* T = smem + w * 4608;                      // 64 rows x stride 72 u16
    const int rsel = lane >> 3, csel = lane & 7;   // out mapping: 8 lanes/row
    if (reg < 2) {
        const float2* tab = reg ? tabk : tabq;     // scale folded into tabq
        u16* dstb = reg ? Kb : Qb;
#pragma unroll
        for (int mi = 0; mi < 4; ++mi) {
#pragma unroll
            for (int r = 0; r < 4; ++r) {
                const int m = m0 + wm * 64 + mi * 16 + quad * 4 + r;  // b*SEQ+n
                const int2 pp = *(const int2*)(pos + m * 2);
                const float2 ty = tab[pp.x * 16 + l15];
                const float2 tx = tab[pp.y * 16 + l15];
                const float x1 = acc[mi][0][r], x2 = acc[mi][1][r];
                const float y1 = acc[mi][2][r], y2 = acc[mi][3][r];
                const int ml = (mi * 16 + quad * 4 + r) * 72;
                T[ml + l15]      = f2bf(x1 * ty.x - x2 * ty.y);
                T[ml + l15 + 16] = f2bf(x1 * ty.y + x2 * ty.x);
                T[ml + l15 + 32] = f2bf(y1 * tx.x - y2 * tx.y);
                T[ml + l15 + 48] = f2bf(y1 * tx.y + y2 * tx.x);
            }
        }
        // same-wave LDS RAW (DS in-order per wave): read rows, 1KB/inst stores
        const int mbase = m0 + wm * 64;
        const int bh = (mbase >> 11) * NH + h;
        const int nbase = mbase & 2047;
#pragma unroll
        for (int j = 0; j < 8; ++j) {
            const int row = rsel + j * 8;
            u16* gp = dstb + ((size_t)bh * SEQ + nbase + row) * 64 + csel * 8;
            *(uint4*)gp = *(const uint4*)&T[row * 72 + csel * 8];
        }
    } else {
        // V: transpose 64x64 (rows = head-dim d) -> Vt[bh][d][n]
#pragma unroll
        for (int mi = 0; mi < 4; ++mi)
#pragma unroll
            for (int nj = 0; nj < 4; ++nj)
#pragma unroll
                for (int r = 0; r < 4; ++r)
                    T[(nj * 16 + l15) * 72 + mi * 16 + quad * 4 + r] =
                        f2bf(acc[mi][nj][r]);
        const int bh = (m0 >> 11) * NH + h;
        const int nbase = (m0 & 2047) + wm * 64;
#pragma unroll
        for (int j = 0; j < 8; ++j) {
            const int d = rsel + j * 8;
            u16* gp = Vt + ((size_t)bh * 64 + d) * SEQ + nbase + csel * 8;
            *(uint4*)gp = *(const uint4*)&T[d * 72 + csel * 8];
        }
    }
}

// ---------------------------------------------------------------------------
// Flash attention: bf16 MFMA, softmax-lite (exp2 only, no max), additive
// split-K=4 (R10: occupancy was the bound — 4 blocks/CU, nothing saturated).
// Grid 2048 1-D, XCD-grouped decode: the 16 q-blocks sharing one (bh,z) K/V
// tile land on one XCD's L2. LDS 32KB -> 5 blocks/CU; launch_bounds(256,5)
// budgets VGPR<=102 for 5 waves/SIMD. Opart splits 2,3 live in d_out scratch
// (dead until gemm_proj). In-register P repack (R9) retained.
// ---------------------------------------------------------------------------
__global__ __launch_bounds__(256, 5) void attn_mfma(const u16* __restrict__ Qb,
                                                    const u16* __restrict__ Kb,
                                                    const u16* __restrict__ Vt,
                                                    u16* __restrict__ Op01,
                                                    u16* __restrict__ Op23,
                                                    float* __restrict__ lpart) {
    __shared__ u16 Ks[2][4096];
    __shared__ u16 Vs[2][4096];
    const int t = threadIdx.x, lane = t & 63, w = t >> 6;
    const int l15 = lane & 15, quad = lane >> 4;

    // XCD-grouped decode: id -> (xcd c, group-on-xcd j, q-block xq)
    const int id = blockIdx.x;
    const int c  = id & 7, r = id >> 3;
    const int j  = r >> 4, xq = r & 15;
    const int g  = c + 8 * j;          // 0..127 = bh + 32*z
    const int bh = g & 31;
    const int z  = g >> 5;             // 0..3
    const int q0 = xq * 128;

    const int rowA = t >> 3, vA = t & 7;
    const int giA = (vA - rowA) & 7;
    const int rowB = rowA + 32;
    const int giB = (vA - rowB) & 7;

    const size_t kbase = (size_t)bh * SEQ * 64;   // Kb: [bh][n][d]
    const size_t vbase = (size_t)bh * 64 * SEQ;   // Vt: [bh][d][n]

    const uint4 ones_u = {0x3F803F80u, 0x3F803F80u, 0x3F803F80u, 0x3F803F80u};
    const bf16x8 onesf = __builtin_bit_cast(bf16x8, ones_u);

    bf16x8 aq[2][2];
#pragma unroll
    for (int mi = 0; mi < 2; ++mi)
#pragma unroll
        for (int ks = 0; ks < 2; ++ks)
            aq[mi][ks] = ld_frag(Qb + ((size_t)bh * SEQ + q0 + w * 32 + mi * 16 + l15) * 64
                                 + ks * 32 + quad * 8);

    // stage tile kt into buffer buf (swizzled dest cols, matching frag reads)
#define STAGE(kt_, buf_)                                                          \
    {                                                                             \
        const int k0_ = z * 512 + (kt_) * 64;                                     \
        gld_lds16(Kb + kbase + (size_t)(k0_ + rowA) * 64 + giA * 8,               \
                  &Ks[buf_][t * 8]);                                              \
        gld_lds16(Kb + kbase + (size_t)(k0_ + rowB) * 64 + giB * 8,               \
                  &Ks[buf_][2048 + t * 8]);                                       \
        gld_lds16(Vt + vbase + (size_t)rowA * SEQ + k0_ + giA * 8,                \
                  &Vs[buf_][t * 8]);                                              \
        gld_lds16(Vt + vbase + (size_t)rowB * SEQ + k0_ + giB * 8,                \
                  &Vs[buf_][2048 + t * 8]);                                       \
    }

    STAGE(0, 0)

    f32x4 oacc[2][4] = {};
    f32x4 lacc[2] = {};

    for (int kt = 0; kt < 8; ++kt) {
        __syncthreads();                 // drains own prefetch (vmcnt 0) + sync
        if (kt + 1 < 8) STAGE(kt + 1, (kt + 1) & 1)
        const u16* ksm = Ks[kt & 1];
        const u16* vsm = Vs[kt & 1];

        // S^T = K Q^T : lane holds (q = l15, k = nk*16 + quad*4 + r)
        f32x4 sacc[2][4] = {};
        __builtin_amdgcn_s_setprio(1);
#pragma unroll
        for (int ks = 0; ks < 2; ++ks)
#pragma unroll
            for (int nk = 0; nk < 4; ++nk) {
                const int rK = nk * 16 + l15;
                const bf16x8 kf = ld_frag(ksm + (rK * 8 + (((ks * 4 + quad) + rK) & 7)) * 8);
                sacc[0][nk] = mfma16(kf, aq[0][ks], sacc[0][nk]);
                sacc[1][nk] = mfma16(kf, aq[1][ks], sacc[1][nk]);
            }
        __builtin_amdgcn_s_setprio(0);

        // softmax-lite + in-register repack to PV A-frags.
        bf16x8 pa[2][2];
#pragma unroll
        for (int mi = 0; mi < 2; ++mi) {
            u32 W[4][2];
#pragma unroll
            for (int nk = 0; nk < 4; ++nk) {
                const float p0 = fexp2(sacc[mi][nk][0]);
                const float p1 = fexp2(sacc[mi][nk][1]);
                const float p2 = fexp2(sacc[mi][nk][2]);
                const float p3 = fexp2(sacc[mi][nk][3]);
                W[nk][0] = pkbf(p0, p1);
                W[nk][1] = pkbf(p2, p3);
            }
            u32 t0[4], t1[4];
            {
                u32 a = W[0][0], cc = W[1][0];
                pl32swap(a, cc); pl16swap(a, cc);
                t0[0] = a; t0[2] = cc;
            }
            {
                u32 a = W[0][1], cc = W[1][1];
                pl32swap(a, cc); pl16swap(a, cc);
                t0[1] = a; t0[3] = cc;
            }
            {
                u32 a = W[2][0], cc = W[3][0];
                pl32swap(a, cc); pl16swap(a, cc);
                t1[0] = a; t1[2] = cc;
            }
            {
                u32 a = W[2][1], cc = W[3][1];
                pl32swap(a, cc); pl16swap(a, cc);
                t1[1] = a; t1[3] = cc;
            }
            uint4 u0; u0.x = t0[0]; u0.y = t0[1]; u0.z = t0[2]; u0.w = t0[3];
            uint4 u1; u1.x = t1[0]; u1.y = t1[1]; u1.z = t1[2]; u1.w = t1[3];
            pa[mi][0] = __builtin_bit_cast(bf16x8, u0);
            pa[mi][1] = __builtin_bit_cast(bf16x8, u1);
        }

        // O += P V ; l += P @ ones
        __builtin_amdgcn_s_setprio(1);
        lacc[0] = mfma16(pa[0][0], onesf, lacc[0]);
        lacc[0] = mfma16(pa[0][1], onesf, lacc[0]);
        lacc[1] = mfma16(pa[1][0], onesf, lacc[1]);
        lacc[1] = mfma16(pa[1][1], onesf, lacc[1]);
#pragma unroll
        for (int ks = 0; ks < 2; ++ks)
#pragma unroll
            for (int nj = 0; nj < 4; ++nj) {
                const int rV = nj * 16 + l15;
                const bf16x8 vf = ld_frag(vsm + (rV * 8 + (((ks * 4 + quad) + rV) & 7)) * 8);
                oacc[0][nj] = mfma16(pa[0][ks], vf, oacc[0][nj]);
                oacc[1][nj] = mfma16(pa[1][ks], vf, oacc[1][nj]);
            }
        __builtin_amdgcn_s_setprio(0);
    }
#undef STAGE

    // epilogue: lacc C-layout (row = quad*4+r, value replicated over cols)
    u16* ob = (z < 2 ? Op01 : Op23) + (size_t)(z & 1) * 4194304;
#pragma unroll
    for (int mi = 0; mi < 2; ++mi)
#pragma unroll
        for (int r = 0; r < 4; ++r) {
            const int qrow = q0 + w * 32 + mi * 16 + quad * 4 + r;
            if (l15 == 0)
                lpart[((size_t)z * 32 + bh) * SEQ + qrow] = lacc[mi][r];
            const size_t orow = ((size_t)bh * SEQ + qrow) * 64;
#pragma unroll
            for (int nj = 0; nj < 4; ++nj)
                ob[orow + nj * 16 + l15] = f2bf(oacc[mi][nj][r]);
        }
}

// ---------------------------------------------------------------------------
// Merge the four K-splits: O = sum(Oz) / sum(lz), repack to (B,N,H*DH) bf16.
// ---------------------------------------------------------------------------
__global__ __launch_bounds__(256) void merge_kernel(const u16* __restrict__ Op01,
                                                    const u16* __restrict__ Op23,
                                                    const float* __restrict__ lpart,
                                                    u16* __restrict__ Ob) {
    const int gid = blockIdx.x * 256 + threadIdx.x;     // 1,048,576 total
    const int d4 = gid & 15, q = (gid >> 4) & 2047, bh = gid >> 15;
    const size_t ibase = ((size_t)bh * SEQ + q) * 64 + d4 * 4;
    const float inv = 1.0f / (lpart[(size_t)bh * SEQ + q] +
                              lpart[((size_t)32 + bh) * SEQ + q] +
                              lpart[((size_t)64 + bh) * SEQ + q] +
                              lpart[((size_t)96 + bh) * SEQ + q]);
    const ushort4 a = *(const ushort4*)(Op01 + ibase);
    const ushort4 b = *(const ushort4*)(Op01 + ibase + 4194304);
    const ushort4 cc = *(const ushort4*)(Op23 + ibase);
    const ushort4 d = *(const ushort4*)(Op23 + ibase + 4194304);
    ushort4 o;
    o.x = f2bf((bf2f(a.x) + bf2f(b.x) + bf2f(cc.x) + bf2f(d.x)) * inv);
    o.y = f2bf((bf2f(a.y) + bf2f(b.y) + bf2f(cc.y) + bf2f(d.y)) * inv);
    o.z = f2bf((bf2f(a.z) + bf2f(b.z) + bf2f(cc.z) + bf2f(d.z)) * inv);
    o.w = f2bf((bf2f(a.w) + bf2f(b.w) + bf2f(cc.w) + bf2f(d.w)) * inv);
    const int b_ = bh >> 4, h = bh & 15;
    *(ushort4*)(Ob + ((size_t)(b_ * SEQ + q)) * CH + h * 64 + d4 * 4) = o;
}

// ---------------------------------------------------------------------------
// Proj GEMM: 64x128 tile (grid 8 x 64 = 512 blocks = 2/CU), double-buffered,
// direct fp32 stores + bias. Wave (wm,wn): rows [wm*32,+32), cols [wn*64,+64);
// acc[2][4]. 8 MFMA + 6 frag-loads per k-iter.
// ---------------------------------------------------------------------------
__global__ __launch_bounds__(256) void gemm_proj(const u16* __restrict__ A,
                                                 const u16* __restrict__ Bw,
                                                 const float* __restrict__ bias,
                                                 float* __restrict__ C) {
    __shared__ u16 smem[12288];   // As dbuf 2x2048 u16; Bs dbuf 2x4096 u16
    const int t = threadIdx.x, lane = t & 63, w = t >> 6;
    const int l15 = lane & 15, quad = lane >> 4;
    const int wm = w >> 1, wn = w & 1;
    const int m0 = blockIdx.y * 64, n0 = blockIdx.x * 128;
    const int K = CH, N = CH;

    const int row0 = t >> 2, v0 = t & 3;              // A rows 0..63, B rows 0..63
    const int gi0 = (v0 - (row0 >> 1)) & 3;
    const int row1 = row0 + 64;                       // B rows 64..127
    const int gi1 = (v0 - (row1 >> 1)) & 3;

    const u16* A0 = A  + (size_t)(m0 + row0) * K + gi0 * 8;
    const u16* B0 = Bw + (size_t)(n0 + row0) * K + gi0 * 8;
    const u16* B1 = Bw + (size_t)(n0 + row1) * K + gi1 * 8;

    // buffers (u16 offsets): As: buf*2048; Bs base 4096: buf*4096
    gld_lds16(A0, smem + t * 8);
    gld_lds16(B0, smem + 4096 + t * 8);
    gld_lds16(B1, smem + 4096 + 2048 + t * 8);

    f32x4 acc[2][4] = {};
    for (int kt = 0; kt < K / 32; ++kt) {
        __syncthreads();
        const int curA = (kt & 1) * 2048;
        const int curB = 4096 + (kt & 1) * 4096;
        if (kt + 1 < K / 32) {
            const int off = (kt + 1) * 32;
            const int nxtA = ((kt + 1) & 1) * 2048;
            const int nxtB = 4096 + ((kt + 1) & 1) * 4096;
            gld_lds16(A0 + off, smem + nxtA + t * 8);
            gld_lds16(B0 + off, smem + nxtB + t * 8);
            gld_lds16(B1 + off, smem + nxtB + 2048 + t * 8);
        }
        const u16* as = smem + curA;
        const u16* bs = smem + curB;
        bf16x8 af[2], bfv[4];
#pragma unroll
        for (int mi = 0; mi < 2; ++mi) {
            const int r = wm * 32 + mi * 16 + l15;    // 0..63
            af[mi] = ld_frag(as + (r * 4 + ((quad + (r >> 1)) & 3)) * 8);
        }
#pragma unroll
        for (int nj = 0; nj < 4; ++nj) {
            const int r = wn * 64 + nj * 16 + l15;    // 0..127
            bfv[nj] = ld_frag(bs + (r * 4 + ((quad + (r >> 1)) & 3)) * 8);
        }
#pragma unroll
        for (int mi = 0; mi < 2; ++mi)
#pragma unroll
            for (int nj = 0; nj < 4; ++nj)
                acc[mi][nj] = mfma16(af[mi], bfv[nj], acc[mi][nj]);
    }
#pragma unroll
    for (int mi = 0; mi < 2; ++mi)
#pragma unroll
        for (int nj = 0; nj < 4; ++nj) {
            const int n = n0 + wn * 64 + nj * 16 + l15;
            const float bv = bias[n];
#pragma unroll
            for (int r = 0; r < 4; ++r) {
                const int m = m0 + wm * 32 + mi * 16 + quad * 4 + r;
                C[(size_t)m * N + n] = acc[mi][nj][r] + bv;
            }
        }
}

// ---------------------------------------------------------------------------
// Workspace layout (u16 offsets; extent 29,360,128 u16 = 56.00 MiB, proven):
//   [0         ..  4,194,304)  x_bf      (dead after qkv)
//   [4,194,304 ..  7,340,032)  wq_bf     -> lpart after qkv (4 splits, 2MB)
//   [7,340,032 ..  8,388,608)  wp_bf     (live until proj)
//   [8,388,608 .. 12,582,912)  Qb        -> attn_bf after attn (merge out)
//   [12,582,912.. 16,777,216)  Kb
//   [16,777,216.. 20,971,520)  Vt
//   [20,971,520.. 29,360,128)  Opart z=0,1 (2 x 4.19M u16); first 16 KB
//                              doubles as tabq/tabk (dead before attn writes)
//   d_out (16 MB fp32)         Opart z=2,3 scratch (dead until gemm_proj)
// ---------------------------------------------------------------------------
extern "C" void kernel_launch(void* const* d_in, const int* in_sizes, int n_in,
                              void* d_out, int out_size, void* d_ws, size_t ws_size,
                              hipStream_t stream) {
    const float* x      = (const float*)d_in[0];
    const int*   pos    = (const int*)d_in[1];
    const float* qkv_w  = (const float*)d_in[2];
    const float* proj_w = (const float*)d_in[3];
    const float* proj_b = (const float*)d_in[4];
    float* out = (float*)d_out;

    u16* ws = (u16*)d_ws;
    u16* x_bf    = ws;
    u16* wq_bf   = ws + 4194304;
    float* lpart = (float*)(ws + 4194304);      // aliases wq_bf (dead after qkv)
    u16* wp_bf   = ws + 7340032;
    u16* Qb      = ws + 8388608;
    u16* attn_bf = ws + 8388608;                // aliases Qb (dead after attn)
    u16* Kb      = ws + 12582912;
    u16* Vt      = ws + 16777216;
    u16* Op01    = ws + 20971520;
    u16* Op23    = (u16*)d_out;                 // scratch: dead until gemm_proj
    float2* tabq = (float2*)(ws + 20971520);    // aliases Op01 head (dead by attn)
    float2* tabk = (float2*)(ws + 20971520 + 4096);

    const int M = BB * SEQ;  // 4096

    convert_kernel<<<8196, 256, 0, stream>>>(x, qkv_w, proj_w, x_bf, wq_bf, wp_bf,
                                             tabq, tabk);
    gemm_qkv_rope<<<dim3(3 * CH / 128, M / 128), 256, 0, stream>>>(
        x_bf, wq_bf, pos, tabq, tabk, Qb, Kb, Vt);
    attn_mfma<<<2048, 256, 0, stream>>>(Qb, Kb, Vt, Op01, Op23, lpart);
    merge_kernel<<<4096, 256, 0, stream>>>(Op01, Op23, lpart, attn_bf);
    gemm_proj<<<dim3(CH / 128, M / 64), 256, 0, stream>>>(
        attn_bf, wp_bf, proj_b, out);
}

// Round 4
// 201.516 us; speedup vs baseline: 1.3157x; 1.3157x over previous
//
#include <hip/hip_runtime.h>
#include <cmath>

typedef unsigned short u16;
typedef unsigned int   u32;
typedef __attribute__((ext_vector_type(8))) __bf16 bf16x8;
typedef __attribute__((ext_vector_type(2))) __bf16 bf16x2;
typedef __attribute__((ext_vector_type(4))) float  f32x4;
typedef __attribute__((ext_vector_type(2))) unsigned int u32x2;

constexpr int BB = 2, SEQ = 2048, CH = 1024, NH = 16, DH = 64;

__device__ inline u16 f2bf(float f) {            // RNE fp32 -> bf16
    u32 u = __builtin_bit_cast(u32, f);
    u += 0x7FFF + ((u >> 16) & 1);
    return (u16)(u >> 16);
}
__device__ inline float bf2f(u16 b) { return __builtin_bit_cast(float, (u32)b << 16); }
__device__ inline u32 pkbf(float a, float b) {   // pack two RNE bf16 into u32
#if __has_builtin(__builtin_amdgcn_cvt_pk_bf16_f32)
    bf16x2 r = __builtin_amdgcn_cvt_pk_bf16_f32(a, b);
    return __builtin_bit_cast(u32, r);
#else
    return (u32)f2bf(a) | ((u32)f2bf(b) << 16);
#endif
}
__device__ inline float fexp2(float x) {
#if __has_builtin(__builtin_amdgcn_exp2f)
    return __builtin_amdgcn_exp2f(x);
#else
    return exp2f(x);
#endif
}

// permlane swaps (gfx950). P32: a'=[a0,a1,b0,b1] b'=[a2,a3,b2,b3] (16-lane rows)
// P16: a'=[a0,b0,a2,b2] b'=[a1,b1,a3,b3]
__device__ inline void pl32swap(u32& a, u32& b) {
#if __has_builtin(__builtin_amdgcn_permlane32_swap)
    u32x2 r = __builtin_amdgcn_permlane32_swap(a, b, false, false);
    a = r.x; b = r.y;
#else
    const int ln = threadIdx.x & 63;
    u32 ax = (u32)__shfl_xor((int)a, 32), bx = (u32)__shfl_xor((int)b, 32);
    u32 na = (ln & 32) ? bx : a;
    u32 nb = (ln & 32) ? b : ax;
    a = na; b = nb;
#endif
}
__device__ inline void pl16swap(u32& a, u32& b) {
#if __has_builtin(__builtin_amdgcn_permlane16_swap)
    u32x2 r = __builtin_amdgcn_permlane16_swap(a, b, false, false);
    a = r.x; b = r.y;
#else
    const int ln = threadIdx.x & 63;
    u32 ax = (u32)__shfl_xor((int)a, 16), bx = (u32)__shfl_xor((int)b, 16);
    u32 na = (ln & 16) ? bx : a;
    u32 nb = (ln & 16) ? b : ax;
    a = na; b = nb;
#endif
}

__device__ inline void gld_lds16(const void* g, void* l) {
    __builtin_amdgcn_global_load_lds((const __attribute__((address_space(1))) void*)g,
                                     (__attribute__((address_space(3))) void*)l, 16, 0, 0);
}
__device__ inline f32x4 mfma16(bf16x8 a, bf16x8 b, f32x4 c) {
    return __builtin_amdgcn_mfma_f32_16x16x32_bf16(a, b, c, 0, 0, 0);
}
__device__ inline bf16x8 ld_frag(const u16* p) {
    return __builtin_bit_cast(bf16x8, *(const uint4*)p);
}

// ---------------------------------------------------------------------------
// fp32 -> bf16 conversion for x, qkv_w, proj_w + RoPE sin/cos table gen.
// ---------------------------------------------------------------------------
__global__ __launch_bounds__(256) void convert_kernel(const float* __restrict__ x,
                                                      const float* __restrict__ wq,
                                                      const float* __restrict__ wp,
                                                      u16* __restrict__ xb,
                                                      u16* __restrict__ wqb,
                                                      u16* __restrict__ wpb,
                                                      float2* __restrict__ tabq,
                                                      float2* __restrict__ tabk) {
    const int q = blockIdx.x * 256 + threadIdx.x;   // quad index
    if (q >= 2097152) {                             // table-gen tail: 1024 threads
        const int idx = q - 2097152;
        if (idx < 1024) {
            const int p = idx >> 4, i = idx & 15;
            const float f = exp2f(-(float)i * 0.41524101186092f);  // log2(100)/16
            float s, c;
            sincosf((float)p * f, &s, &c);
            tabk[idx] = make_float2(c, s);
            tabq[idx] = make_float2(c * 0.18033688011112042f,
                                    s * 0.18033688011112042f);
        }
        return;
    }
    const float* src; u16* dst; int idx;
    if (q < 1048576)            { src = x;  dst = xb;  idx = q; }
    else if (q < 1048576+786432){ src = wq; dst = wqb; idx = q - 1048576; }
    else                        { src = wp; dst = wpb; idx = q - 1048576 - 786432; }
    float4 v = *(const float4*)(src + (size_t)idx * 4);
    ushort4 o; o.x = f2bf(v.x); o.y = f2bf(v.y); o.z = f2bf(v.z); o.w = f2bf(v.w);
    *(ushort4*)(dst + (size_t)idx * 4) = o;
}

// ---------------------------------------------------------------------------
// Fused QKV GEMM + RoPE + head-major repack, double-buffered staging,
// LDS-transpose epilogue (all three outputs written as coalesced 16B chunks).
// ---------------------------------------------------------------------------
__global__ __launch_bounds__(256) void gemm_qkv_rope(const u16* __restrict__ A,
                                                     const u16* __restrict__ Bw,
                                                     const int* __restrict__ pos,
                                                     const float2* __restrict__ tabq,
                                                     const float2* __restrict__ tabk,
                                                     u16* __restrict__ Qb,
                                                     u16* __restrict__ Kb,
                                                     u16* __restrict__ Vt) {
    __shared__ u16 smem[18432];   // dbuf staging [0,16384); epilogue T = 4 x 4608
    const int t = threadIdx.x, lane = t & 63, w = t >> 6;
    const int l15 = lane & 15, quad = lane >> 4;
    const int wm = w >> 1, wn = w & 1;
    const int m0 = blockIdx.y * 128, n0 = blockIdx.x * 128;
    const int K = CH;

    const int row0 = t >> 2, v0 = t & 3;
    const int gi0 = (v0 - (row0 >> 1)) & 3;
    const int row1 = row0 + 64;
    const int gi1 = (v0 - (row1 >> 1)) & 3;

    const u16* A0 = A  + (size_t)(m0 + row0) * K + gi0 * 8;
    const u16* A1 = A  + (size_t)(m0 + row1) * K + gi1 * 8;
    const u16* B0 = Bw + (size_t)(n0 + row0) * K + gi0 * 8;
    const u16* B1 = Bw + (size_t)(n0 + row1) * K + gi1 * 8;

    gld_lds16(A0, smem + t * 8);
    gld_lds16(A1, smem + 2048 + t * 8);
    gld_lds16(B0, smem + 8192 + t * 8);
    gld_lds16(B1, smem + 10240 + t * 8);

    f32x4 acc[4][4] = {};
    for (int kt = 0; kt < K / 32; ++kt) {
        __syncthreads();          // drains own prefetch (vmcnt 0) + block sync
        const int cur = (kt & 1) * 4096;
        if (kt + 1 < K / 32) {
            const int off = (kt + 1) * 32;
            const int nxt = ((kt + 1) & 1) * 4096;
            gld_lds16(A0 + off, smem + nxt + t * 8);
            gld_lds16(A1 + off, smem + nxt + 2048 + t * 8);
            gld_lds16(B0 + off, smem + 8192 + nxt + t * 8);
            gld_lds16(B1 + off, smem + 8192 + nxt + 2048 + t * 8);
        }
        const u16* as = smem + cur;
        const u16* bs = smem + 8192 + cur;
        bf16x8 af[4], bfv[4];
#pragma unroll
        for (int mi = 0; mi < 4; ++mi) {
            const int r = wm * 64 + mi * 16 + l15;
            af[mi] = ld_frag(as + (r * 4 + ((quad + (r >> 1)) & 3)) * 8);
        }
#pragma unroll
        for (int nj = 0; nj < 4; ++nj) {
            const int r = wn * 64 + nj * 16 + l15;
            bfv[nj] = ld_frag(bs + (r * 4 + ((quad + (r >> 1)) & 3)) * 8);
        }
#pragma unroll
        for (int mi = 0; mi < 4; ++mi)
#pragma unroll
            for (int nj = 0; nj < 4; ++nj)
                acc[mi][nj] = mfma16(af[mi], bfv[nj], acc[mi][nj]);
    }

    const int reg = n0 >> 10;                      // 0=q, 1=k, 2=v (block-uniform)
    const int h   = ((n0 & 1023) >> 6) + wn;       // wave's head
    __syncthreads();                               // staging fully consumed
    u16* T = smem + w * 4608;                      // 64 rows x stride 72 u16
    const int rsel = lane >> 3, csel = lane & 7;   // out mapping: 8 lanes/row
    if (reg < 2) {
        const float2* tab = reg ? tabk : tabq;     // scale folded into tabq
        u16* dstb = reg ? Kb : Qb;
#pragma unroll
        for (int mi = 0; mi < 4; ++mi) {
#pragma unroll
            for (int r = 0; r < 4; ++r) {
                const int m = m0 + wm * 64 + mi * 16 + quad * 4 + r;  // b*SEQ+n
                const int2 pp = *(const int2*)(pos + m * 2);
                const float2 ty = tab[pp.x * 16 + l15];
                const float2 tx = tab[pp.y * 16 + l15];
                const float x1 = acc[mi][0][r], x2 = acc[mi][1][r];
                const float y1 = acc[mi][2][r], y2 = acc[mi][3][r];
                const int ml = (mi * 16 + quad * 4 + r) * 72;
                T[ml + l15]      = f2bf(x1 * ty.x - x2 * ty.y);
                T[ml + l15 + 16] = f2bf(x1 * ty.y + x2 * ty.x);
                T[ml + l15 + 32] = f2bf(y1 * tx.x - y2 * tx.y);
                T[ml + l15 + 48] = f2bf(y1 * tx.y + y2 * tx.x);
            }
        }
        // same-wave LDS RAW (DS in-order per wave): read rows, 1KB/inst stores
        const int mbase = m0 + wm * 64;
        const int bh = (mbase >> 11) * NH + h;
        const int nbase = mbase & 2047;
#pragma unroll
        for (int j = 0; j < 8; ++j) {
            const int row = rsel + j * 8;
            u16* gp = dstb + ((size_t)bh * SEQ + nbase + row) * 64 + csel * 8;
            *(uint4*)gp = *(const uint4*)&T[row * 72 + csel * 8];
        }
    } else {
        // V: transpose 64x64 (rows = head-dim d) -> Vt[bh][d][n]
#pragma unroll
        for (int mi = 0; mi < 4; ++mi)
#pragma unroll
            for (int nj = 0; nj < 4; ++nj)
#pragma unroll
                for (int r = 0; r < 4; ++r)
                    T[(nj * 16 + l15) * 72 + mi * 16 + quad * 4 + r] =
                        f2bf(acc[mi][nj][r]);
        const int bh = (m0 >> 11) * NH + h;
        const int nbase = (m0 & 2047) + wm * 64;
#pragma unroll
        for (int j = 0; j < 8; ++j) {
            const int d = rsel + j * 8;
            u16* gp = Vt + ((size_t)bh * 64 + d) * SEQ + nbase + csel * 8;
            *(uint4*)gp = *(const uint4*)&T[d * 72 + csel * 8];
        }
    }
}

// ---------------------------------------------------------------------------
// Flash attention: bf16 MFMA, softmax-lite (exp2 only, no max), additive
// split-K=2 (Opart fully ws-resident — R10 lesson: d_out scratch write-
// amplifies 20x). R11: occupancy attack via q-tile 64 (16 rows/wave):
// grid 2048 1-D XCD-grouped, single-buffered 16KB LDS, launch_bounds(256,8)
// -> 8 blocks/CU (was 4). In-register P repack (R9) retained.
// ---------------------------------------------------------------------------
__global__ __launch_bounds__(256, 8) void attn_mfma(const u16* __restrict__ Qb,
                                                    const u16* __restrict__ Kb,
                                                    const u16* __restrict__ Vt,
                                                    u16* __restrict__ Opart,
                                                    float* __restrict__ lpart) {
    __shared__ u16 Ks[4096];
    __shared__ u16 Vs[4096];
    const int t = threadIdx.x, lane = t & 63, w = t >> 6;
    const int l15 = lane & 15, quad = lane >> 4;

    // XCD-grouped decode: id -> (xcd c, combo j, q-block xq). 8 combos/XCD,
    // 32 q-blocks/combo share one (bh,z) K/V range -> 2MB L2 set per XCD.
    const int id = blockIdx.x;
    const int c  = id & 7, r_ = id >> 3;
    const int j  = r_ >> 5, xq = r_ & 31;
    const int g  = c + 8 * j;          // 0..63 = bh + 32*z
    const int bh = g & 31;
    const int z  = g >> 5;             // 0..1
    const int q0 = xq * 64;

    const int rowA = t >> 3, vA = t & 7;
    const int giA = (vA - rowA) & 7;
    const int rowB = rowA + 32;
    const int giB = (vA - rowB) & 7;

    const size_t kbase = (size_t)bh * SEQ * 64;   // Kb: [bh][n][d]
    const size_t vbase = (size_t)bh * 64 * SEQ;   // Vt: [bh][d][n]

    const uint4 ones_u = {0x3F803F80u, 0x3F803F80u, 0x3F803F80u, 0x3F803F80u};
    const bf16x8 onesf = __builtin_bit_cast(bf16x8, ones_u);

    bf16x8 aq[2];
#pragma unroll
    for (int ks = 0; ks < 2; ++ks)
        aq[ks] = ld_frag(Qb + ((size_t)bh * SEQ + q0 + w * 16 + l15) * 64
                         + ks * 32 + quad * 8);

    // stage tile kt (16KB: K 8KB + V 8KB, swizzled dest cols match frag reads)
#define STAGE(kt_)                                                                \
    {                                                                             \
        const int k0_ = z * 1024 + (kt_) * 64;                                    \
        gld_lds16(Kb + kbase + (size_t)(k0_ + rowA) * 64 + giA * 8,               \
                  &Ks[t * 8]);                                                    \
        gld_lds16(Kb + kbase + (size_t)(k0_ + rowB) * 64 + giB * 8,               \
                  &Ks[2048 + t * 8]);                                             \
        gld_lds16(Vt + vbase + (size_t)rowA * SEQ + k0_ + giA * 8,                \
                  &Vs[t * 8]);                                                    \
        gld_lds16(Vt + vbase + (size_t)rowB * SEQ + k0_ + giB * 8,                \
                  &Vs[2048 + t * 8]);                                             \
    }

    f32x4 oacc[4] = {};
    f32x4 lacc = {};

    for (int kt = 0; kt < 16; ++kt) {
        __syncthreads();                 // all waves done reading previous tile
        STAGE(kt)
        __syncthreads();                 // staged data visible (vmcnt drained)

        // S^T = K Q^T : lane holds (q = l15, k = nk*16 + quad*4 + r)
        f32x4 sacc[4] = {};
        __builtin_amdgcn_s_setprio(1);
#pragma unroll
        for (int ks = 0; ks < 2; ++ks)
#pragma unroll
            for (int nk = 0; nk < 4; ++nk) {
                const int rK = nk * 16 + l15;
                const bf16x8 kf = ld_frag(Ks + (rK * 8 + (((ks * 4 + quad) + rK) & 7)) * 8);
                sacc[nk] = mfma16(kf, aq[ks], sacc[nk]);
            }
        __builtin_amdgcn_s_setprio(0);

        // softmax-lite + in-register repack to PV A-frags.
        bf16x8 pa[2];
        {
            u32 W[4][2];
#pragma unroll
            for (int nk = 0; nk < 4; ++nk) {
                const float p0 = fexp2(sacc[nk][0]);
                const float p1 = fexp2(sacc[nk][1]);
                const float p2 = fexp2(sacc[nk][2]);
                const float p3 = fexp2(sacc[nk][3]);
                W[nk][0] = pkbf(p0, p1);
                W[nk][1] = pkbf(p2, p3);
            }
            u32 t0[4], t1[4];
            {
                u32 a = W[0][0], cc = W[1][0];
                pl32swap(a, cc); pl16swap(a, cc);
                t0[0] = a; t0[2] = cc;
            }
            {
                u32 a = W[0][1], cc = W[1][1];
                pl32swap(a, cc); pl16swap(a, cc);
                t0[1] = a; t0[3] = cc;
            }
            {
                u32 a = W[2][0], cc = W[3][0];
                pl32swap(a, cc); pl16swap(a, cc);
                t1[0] = a; t1[2] = cc;
            }
            {
                u32 a = W[2][1], cc = W[3][1];
                pl32swap(a, cc); pl16swap(a, cc);
                t1[1] = a; t1[3] = cc;
            }
            uint4 u0; u0.x = t0[0]; u0.y = t0[1]; u0.z = t0[2]; u0.w = t0[3];
            uint4 u1; u1.x = t1[0]; u1.y = t1[1]; u1.z = t1[2]; u1.w = t1[3];
            pa[0] = __builtin_bit_cast(bf16x8, u0);
            pa[1] = __builtin_bit_cast(bf16x8, u1);
        }

        // O += P V ; l += P @ ones
        __builtin_amdgcn_s_setprio(1);
        lacc = mfma16(pa[0], onesf, lacc);
        lacc = mfma16(pa[1], onesf, lacc);
#pragma unroll
        for (int ks = 0; ks < 2; ++ks)
#pragma unroll
            for (int nj = 0; nj < 4; ++nj) {
                const int rV = nj * 16 + l15;
                const bf16x8 vf = ld_frag(Vs + (rV * 8 + (((ks * 4 + quad) + rV) & 7)) * 8);
                oacc[nj] = mfma16(pa[ks], vf, oacc[nj]);
            }
        __builtin_amdgcn_s_setprio(0);
    }
#undef STAGE

    // epilogue: lacc C-layout (row = quad*4+r, value replicated over cols)
    u16* ob = Opart + (size_t)z * 4194304;
#pragma unroll
    for (int r = 0; r < 4; ++r) {
        const int qrow = q0 + w * 16 + quad * 4 + r;
        if (l15 == 0)
            lpart[((size_t)z * 32 + bh) * SEQ + qrow] = lacc[r];
        const size_t orow = ((size_t)bh * SEQ + qrow) * 64;
#pragma unroll
        for (int nj = 0; nj < 4; ++nj)
            ob[orow + nj * 16 + l15] = f2bf(oacc[nj][r]);
    }
}

// ---------------------------------------------------------------------------
// Merge the two K-splits: O = (O1 + O2) / (l1 + l2), repack to (B,N,H*DH) bf16.
// ---------------------------------------------------------------------------
__global__ __launch_bounds__(256) void merge_kernel(const u16* __restrict__ Opart,
                                                    const float* __restrict__ lpart,
                                                    u16* __restrict__ Ob) {
    const int gid = blockIdx.x * 256 + threadIdx.x;     // 1,048,576 total
    const int d4 = gid & 15, q = (gid >> 4) & 2047, bh = gid >> 15;
    const size_t i1 = ((size_t)bh * SEQ + q) * 64 + d4 * 4;
    const size_t i2 = i1 + 4194304;
    const float inv = 1.0f / (lpart[(size_t)bh * SEQ + q] +
                              lpart[((size_t)32 + bh) * SEQ + q]);
    const ushort4 a = *(const ushort4*)(Opart + i1);
    const ushort4 b = *(const ushort4*)(Opart + i2);
    ushort4 o;
    o.x = f2bf((bf2f(a.x) + bf2f(b.x)) * inv);
    o.y = f2bf((bf2f(a.y) + bf2f(b.y)) * inv);
    o.z = f2bf((bf2f(a.z) + bf2f(b.z)) * inv);
    o.w = f2bf((bf2f(a.w) + bf2f(b.w)) * inv);
    const int b_ = bh >> 4, h = bh & 15;
    *(ushort4*)(Ob + ((size_t)(b_ * SEQ + q)) * CH + h * 64 + d4 * 4) = o;
}

// ---------------------------------------------------------------------------
// Proj GEMM: 64x128 tile (grid 8 x 64 = 512 blocks = 2/CU), double-buffered,
// direct fp32 stores + bias. Wave (wm,wn): rows [wm*32,+32), cols [wn*64,+64);
// acc[2][4]. 8 MFMA + 6 frag-loads per k-iter.
// ---------------------------------------------------------------------------
__global__ __launch_bounds__(256) void gemm_proj(const u16* __restrict__ A,
                                                 const u16* __restrict__ Bw,
                                                 const float* __restrict__ bias,
                                                 float* __restrict__ C) {
    __shared__ u16 smem[12288];   // As dbuf 2x2048 u16; Bs dbuf 2x4096 u16
    const int t = threadIdx.x, lane = t & 63, w = t >> 6;
    const int l15 = lane & 15, quad = lane >> 4;
    const int wm = w >> 1, wn = w & 1;
    const int m0 = blockIdx.y * 64, n0 = blockIdx.x * 128;
    const int K = CH, N = CH;

    const int row0 = t >> 2, v0 = t & 3;              // A rows 0..63, B rows 0..63
    const int gi0 = (v0 - (row0 >> 1)) & 3;
    const int row1 = row0 + 64;                       // B rows 64..127
    const int gi1 = (v0 - (row1 >> 1)) & 3;

    const u16* A0 = A  + (size_t)(m0 + row0) * K + gi0 * 8;
    const u16* B0 = Bw + (size_t)(n0 + row0) * K + gi0 * 8;
    const u16* B1 = Bw + (size_t)(n0 + row1) * K + gi1 * 8;

    // buffers (u16 offsets): As: buf*2048; Bs base 4096: buf*4096
    gld_lds16(A0, smem + t * 8);
    gld_lds16(B0, smem + 4096 + t * 8);
    gld_lds16(B1, smem + 4096 + 2048 + t * 8);

    f32x4 acc[2][4] = {};
    for (int kt = 0; kt < K / 32; ++kt) {
        __syncthreads();
        const int curA = (kt & 1) * 2048;
        const int curB = 4096 + (kt & 1) * 4096;
        if (kt + 1 < K / 32) {
            const int off = (kt + 1) * 32;
            const int nxtA = ((kt + 1) & 1) * 2048;
            const int nxtB = 4096 + ((kt + 1) & 1) * 4096;
            gld_lds16(A0 + off, smem + nxtA + t * 8);
            gld_lds16(B0 + off, smem + nxtB + t * 8);
            gld_lds16(B1 + off, smem + nxtB + 2048 + t * 8);
        }
        const u16* as = smem + curA;
        const u16* bs = smem + curB;
        bf16x8 af[2], bfv[4];
#pragma unroll
        for (int mi = 0; mi < 2; ++mi) {
            const int r = wm * 32 + mi * 16 + l15;    // 0..63
            af[mi] = ld_frag(as + (r * 4 + ((quad + (r >> 1)) & 3)) * 8);
        }
#pragma unroll
        for (int nj = 0; nj < 4; ++nj) {
            const int r = wn * 64 + nj * 16 + l15;    // 0..127
            bfv[nj] = ld_frag(bs + (r * 4 + ((quad + (r >> 1)) & 3)) * 8);
        }
#pragma unroll
        for (int mi = 0; mi < 2; ++mi)
#pragma unroll
            for (int nj = 0; nj < 4; ++nj)
                acc[mi][nj] = mfma16(af[mi], bfv[nj], acc[mi][nj]);
    }
#pragma unroll
    for (int mi = 0; mi < 2; ++mi)
#pragma unroll
        for (int nj = 0; nj < 4; ++nj) {
            const int n = n0 + wn * 64 + nj * 16 + l15;
            const float bv = bias[n];
#pragma unroll
            for (int r = 0; r < 4; ++r) {
                const int m = m0 + wm * 32 + mi * 16 + quad * 4 + r;
                C[(size_t)m * N + n] = acc[mi][nj][r] + bv;
            }
        }
}

// ---------------------------------------------------------------------------
// Workspace layout (u16 offsets; extent 29,360,128 u16 = 56.00 MiB, proven):
//   [0         ..  4,194,304)  x_bf      -> attn_bf after qkv (merge out)
//   [4,194,304 ..  7,340,032)  wq_bf     -> lpart after qkv   (attn out)
//   [7,340,032 ..  8,388,608)  wp_bf     (live until proj)
//   [8,388,608 .. 12,582,912)  Qb
//   [12,582,912.. 16,777,216)  Kb
//   [16,777,216.. 20,971,520)  Vt
//   [20,971,520.. 29,360,128)  Opart (2 splits x 4.19M u16); first 16 KB
//                              doubles as tabq/tabk (dead before attn writes)
// ---------------------------------------------------------------------------
extern "C" void kernel_launch(void* const* d_in, const int* in_sizes, int n_in,
                              void* d_out, int out_size, void* d_ws, size_t ws_size,
                              hipStream_t stream) {
    const float* x      = (const float*)d_in[0];
    const int*   pos    = (const int*)d_in[1];
    const float* qkv_w  = (const float*)d_in[2];
    const float* proj_w = (const float*)d_in[3];
    const float* proj_b = (const float*)d_in[4];
    float* out = (float*)d_out;

    u16* ws = (u16*)d_ws;
    u16* x_bf    = ws;
    u16* attn_bf = ws;                          // aliases x_bf (dead after qkv)
    u16* wq_bf   = ws + 4194304;
    float* lpart = (float*)(ws + 4194304);      // aliases wq_bf (dead after qkv)
    u16* wp_bf   = ws + 7340032;
    u16* Qb      = ws + 8388608;
    u16* Kb      = ws + 12582912;
    u16* Vt      = ws + 16777216;
    u16* Opart   = ws + 20971520;
    float2* tabq = (float2*)(ws + 20971520);    // aliases Opart head (dead by attn)
    float2* tabk = (float2*)(ws + 20971520 + 4096);

    const int M = BB * SEQ;  // 4096

    convert_kernel<<<8196, 256, 0, stream>>>(x, qkv_w, proj_w, x_bf, wq_bf, wp_bf,
                                             tabq, tabk);
    gemm_qkv_rope<<<dim3(3 * CH / 128, M / 128), 256, 0, stream>>>(
        x_bf, wq_bf, pos, tabq, tabk, Qb, Kb, Vt);
    attn_mfma<<<2048, 256, 0, stream>>>(Qb, Kb, Vt, Opart, lpart);
    merge_kernel<<<4096, 256, 0, stream>>>(Opart, lpart, attn_bf);
    gemm_proj<<<dim3(CH / 128, M / 64), 256, 0, stream>>>(
        attn_bf, wp_bf, proj_b, out);
}

// Round 5
// 199.410 us; speedup vs baseline: 1.3296x; 1.0106x over previous
//
#include <hip/hip_runtime.h>
#include <cmath>

typedef unsigned short u16;
typedef unsigned int   u32;
typedef __attribute__((ext_vector_type(8))) __bf16 bf16x8;
typedef __attribute__((ext_vector_type(2))) __bf16 bf16x2;
typedef __attribute__((ext_vector_type(4))) float  f32x4;
typedef __attribute__((ext_vector_type(2))) unsigned int u32x2;

constexpr int BB = 2, SEQ = 2048, CH = 1024, NH = 16, DH = 64;

__device__ inline u16 f2bf(float f) {            // RNE fp32 -> bf16
    u32 u = __builtin_bit_cast(u32, f);
    u += 0x7FFF + ((u >> 16) & 1);
    return (u16)(u >> 16);
}
__device__ inline float bf2f(u16 b) { return __builtin_bit_cast(float, (u32)b << 16); }
__device__ inline u32 pkbf(float a, float b) {   // pack two RNE bf16 into u32
#if __has_builtin(__builtin_amdgcn_cvt_pk_bf16_f32)
    bf16x2 r = __builtin_amdgcn_cvt_pk_bf16_f32(a, b);
    return __builtin_bit_cast(u32, r);
#else
    return (u32)f2bf(a) | ((u32)f2bf(b) << 16);
#endif
}
__device__ inline float fexp2(float x) {
#if __has_builtin(__builtin_amdgcn_exp2f)
    return __builtin_amdgcn_exp2f(x);
#else
    return exp2f(x);
#endif
}

// permlane swaps (gfx950). P32: a'=[a0,a1,b0,b1] b'=[a2,a3,b2,b3] (16-lane rows)
// P16: a'=[a0,b0,a2,b2] b'=[a1,b1,a3,b3]
__device__ inline void pl32swap(u32& a, u32& b) {
#if __has_builtin(__builtin_amdgcn_permlane32_swap)
    u32x2 r = __builtin_amdgcn_permlane32_swap(a, b, false, false);
    a = r.x; b = r.y;
#else
    const int ln = threadIdx.x & 63;
    u32 ax = (u32)__shfl_xor((int)a, 32), bx = (u32)__shfl_xor((int)b, 32);
    u32 na = (ln & 32) ? bx : a;
    u32 nb = (ln & 32) ? b : ax;
    a = na; b = nb;
#endif
}
__device__ inline void pl16swap(u32& a, u32& b) {
#if __has_builtin(__builtin_amdgcn_permlane16_swap)
    u32x2 r = __builtin_amdgcn_permlane16_swap(a, b, false, false);
    a = r.x; b = r.y;
#else
    const int ln = threadIdx.x & 63;
    u32 ax = (u32)__shfl_xor((int)a, 16), bx = (u32)__shfl_xor((int)b, 16);
    u32 na = (ln & 16) ? bx : a;
    u32 nb = (ln & 16) ? b : ax;
    a = na; b = nb;
#endif
}

__device__ inline void gld_lds16(const void* g, void* l) {
    __builtin_amdgcn_global_load_lds((const __attribute__((address_space(1))) void*)g,
                                     (__attribute__((address_space(3))) void*)l, 16, 0, 0);
}
__device__ inline f32x4 mfma16(bf16x8 a, bf16x8 b, f32x4 c) {
    return __builtin_amdgcn_mfma_f32_16x16x32_bf16(a, b, c, 0, 0, 0);
}
__device__ inline bf16x8 ld_frag(const u16* p) {
    return __builtin_bit_cast(bf16x8, *(const uint4*)p);
}

// ---------------------------------------------------------------------------
// fp32 -> bf16 conversion for x, qkv_w, proj_w + RoPE sin/cos table gen.
// ---------------------------------------------------------------------------
__global__ __launch_bounds__(256) void convert_kernel(const float* __restrict__ x,
                                                      const float* __restrict__ wq,
                                                      const float* __restrict__ wp,
                                                      u16* __restrict__ xb,
                                                      u16* __restrict__ wqb,
                                                      u16* __restrict__ wpb,
                                                      float2* __restrict__ tabq,
                                                      float2* __restrict__ tabk) {
    const int q = blockIdx.x * 256 + threadIdx.x;   // quad index
    if (q >= 2097152) {                             // table-gen tail: 1024 threads
        const int idx = q - 2097152;
        if (idx < 1024) {
            const int p = idx >> 4, i = idx & 15;
            const float f = exp2f(-(float)i * 0.41524101186092f);  // log2(100)/16
            float s, c;
            sincosf((float)p * f, &s, &c);
            tabk[idx] = make_float2(c, s);
            tabq[idx] = make_float2(c * 0.18033688011112042f,
                                    s * 0.18033688011112042f);
        }
        return;
    }
    const float* src; u16* dst; int idx;
    if (q < 1048576)            { src = x;  dst = xb;  idx = q; }
    else if (q < 1048576+786432){ src = wq; dst = wqb; idx = q - 1048576; }
    else                        { src = wp; dst = wpb; idx = q - 1048576 - 786432; }
    float4 v = *(const float4*)(src + (size_t)idx * 4);
    ushort4 o; o.x = f2bf(v.x); o.y = f2bf(v.y); o.z = f2bf(v.z); o.w = f2bf(v.w);
    *(ushort4*)(dst + (size_t)idx * 4) = o;
}

// ---------------------------------------------------------------------------
// Fused QKV GEMM + RoPE + head-major repack, double-buffered staging,
// LDS-transpose epilogue (all three outputs written as coalesced 16B chunks).
// ---------------------------------------------------------------------------
__global__ __launch_bounds__(256) void gemm_qkv_rope(const u16* __restrict__ A,
                                                     const u16* __restrict__ Bw,
                                                     const int* __restrict__ pos,
                                                     const float2* __restrict__ tabq,
                                                     const float2* __restrict__ tabk,
                                                     u16* __restrict__ Qb,
                                                     u16* __restrict__ Kb,
                                                     u16* __restrict__ Vt) {
    __shared__ u16 smem[18432];   // dbuf staging [0,16384); epilogue T = 4 x 4608
    const int t = threadIdx.x, lane = t & 63, w = t >> 6;
    const int l15 = lane & 15, quad = lane >> 4;
    const int wm = w >> 1, wn = w & 1;
    const int m0 = blockIdx.y * 128, n0 = blockIdx.x * 128;
    const int K = CH;

    const int row0 = t >> 2, v0 = t & 3;
    const int gi0 = (v0 - (row0 >> 1)) & 3;
    const int row1 = row0 + 64;
    const int gi1 = (v0 - (row1 >> 1)) & 3;

    const u16* A0 = A  + (size_t)(m0 + row0) * K + gi0 * 8;
    const u16* A1 = A  + (size_t)(m0 + row1) * K + gi1 * 8;
    const u16* B0 = Bw + (size_t)(n0 + row0) * K + gi0 * 8;
    const u16* B1 = Bw + (size_t)(n0 + row1) * K + gi1 * 8;

    gld_lds16(A0, smem + t * 8);
    gld_lds16(A1, smem + 2048 + t * 8);
    gld_lds16(B0, smem + 8192 + t * 8);
    gld_lds16(B1, smem + 10240 + t * 8);

    f32x4 acc[4][4] = {};
    for (int kt = 0; kt < K / 32; ++kt) {
        __syncthreads();          // drains own prefetch (vmcnt 0) + block sync
        const int cur = (kt & 1) * 4096;
        if (kt + 1 < K / 32) {
            const int off = (kt + 1) * 32;
            const int nxt = ((kt + 1) & 1) * 4096;
            gld_lds16(A0 + off, smem + nxt + t * 8);
            gld_lds16(A1 + off, smem + nxt + 2048 + t * 8);
            gld_lds16(B0 + off, smem + 8192 + nxt + t * 8);
            gld_lds16(B1 + off, smem + 8192 + nxt + 2048 + t * 8);
        }
        const u16* as = smem + cur;
        const u16* bs = smem + 8192 + cur;
        bf16x8 af[4], bfv[4];
#pragma unroll
        for (int mi = 0; mi < 4; ++mi) {
            const int r = wm * 64 + mi * 16 + l15;
            af[mi] = ld_frag(as + (r * 4 + ((quad + (r >> 1)) & 3)) * 8);
        }
#pragma unroll
        for (int nj = 0; nj < 4; ++nj) {
            const int r = wn * 64 + nj * 16 + l15;
            bfv[nj] = ld_frag(bs + (r * 4 + ((quad + (r >> 1)) & 3)) * 8);
        }
#pragma unroll
        for (int mi = 0; mi < 4; ++mi)
#pragma unroll
            for (int nj = 0; nj < 4; ++nj)
                acc[mi][nj] = mfma16(af[mi], bfv[nj], acc[mi][nj]);
    }

    const int reg = n0 >> 10;                      // 0=q, 1=k, 2=v (block-uniform)
    const int h   = ((n0 & 1023) >> 6) + wn;       // wave's head
    __syncthreads();                               // staging fully consumed
    u16* T = smem + w * 4608;                      // 64 rows x stride 72 u16
    const int rsel = lane >> 3, csel = lane & 7;   // out mapping: 8 lanes/row
    if (reg < 2) {
        const float2* tab = reg ? tabk : tabq;     // scale folded into tabq
        u16* dstb = reg ? Kb : Qb;
#pragma unroll
        for (int mi = 0; mi < 4; ++mi) {
#pragma unroll
            for (int r = 0; r < 4; ++r) {
                const int m = m0 + wm * 64 + mi * 16 + quad * 4 + r;  // b*SEQ+n
                const int2 pp = *(const int2*)(pos + m * 2);
                const float2 ty = tab[pp.x * 16 + l15];
                const float2 tx = tab[pp.y * 16 + l15];
                const float x1 = acc[mi][0][r], x2 = acc[mi][1][r];
                const float y1 = acc[mi][2][r], y2 = acc[mi][3][r];
                const int ml = (mi * 16 + quad * 4 + r) * 72;
                T[ml + l15]      = f2bf(x1 * ty.x - x2 * ty.y);
                T[ml + l15 + 16] = f2bf(x1 * ty.y + x2 * ty.x);
                T[ml + l15 + 32] = f2bf(y1 * tx.x - y2 * tx.y);
                T[ml + l15 + 48] = f2bf(y1 * tx.y + y2 * tx.x);
            }
        }
        // same-wave LDS RAW (DS in-order per wave): read rows, 1KB/inst stores
        const int mbase = m0 + wm * 64;
        const int bh = (mbase >> 11) * NH + h;
        const int nbase = mbase & 2047;
#pragma unroll
        for (int j = 0; j < 8; ++j) {
            const int row = rsel + j * 8;
            u16* gp = dstb + ((size_t)bh * SEQ + nbase + row) * 64 + csel * 8;
            *(uint4*)gp = *(const uint4*)&T[row * 72 + csel * 8];
        }
    } else {
        // V: transpose 64x64 (rows = head-dim d) -> Vt[bh][d][n]
#pragma unroll
        for (int mi = 0; mi < 4; ++mi)
#pragma unroll
            for (int nj = 0; nj < 4; ++nj)
#pragma unroll
                for (int r = 0; r < 4; ++r)
                    T[(nj * 16 + l15) * 72 + mi * 16 + quad * 4 + r] =
                        f2bf(acc[mi][nj][r]);
        const int bh = (m0 >> 11) * NH + h;
        const int nbase = (m0 & 2047) + wm * 64;
#pragma unroll
        for (int j = 0; j < 8; ++j) {
            const int d = rsel + j * 8;
            u16* gp = Vt + ((size_t)bh * 64 + d) * SEQ + nbase + csel * 8;
            *(uint4*)gp = *(const uint4*)&T[d * 72 + csel * 8];
        }
    }
}

// ---------------------------------------------------------------------------
// Flash attention: bf16 MFMA, softmax-lite (exp2 only, no max), additive
// split-K=2. R12: counted-vmcnt TRIPLE-buffered pipeline (T3/T4): raw
// s_barrier (no drain) + s_waitcnt vmcnt(4) keeps next tile's 4 staging
// loads in flight across the barrier — __syncthreads' vmcnt(0) drain was
// the phase-invariant cost (R0/R2/R4 all ~56us regardless of structure).
// 3 buffers make 1-barrier/kt race-free: STAGE(kt+1) writes (kt+1)%3 which
// the slowest wave (past barrier kt-1, reading (kt-1)%3 or kt%3) never
// touches. XCD-grouped decode (R11: FETCH 69->15MB). Reg P-repack (R9).
// ---------------------------------------------------------------------------
__global__ __launch_bounds__(256, 3) void attn_mfma(const u16* __restrict__ Qb,
                                                    const u16* __restrict__ Kb,
                                                    const u16* __restrict__ Vt,
                                                    u16* __restrict__ Opart,
                                                    float* __restrict__ lpart) {
    __shared__ u16 Ks[3][4096];
    __shared__ u16 Vs[3][4096];
    const int t = threadIdx.x, lane = t & 63, w = t >> 6;
    const int l15 = lane & 15, quad = lane >> 4;

    // XCD-grouped decode: 8 (bh,z) combos per XCD, 16 q-blocks per combo.
    const int id = blockIdx.x;
    const int c  = id & 7, r_ = id >> 3;
    const int j  = r_ >> 4, xq = r_ & 15;
    const int g  = c + 8 * j;          // 0..63 = bh + 32*z
    const int bh = g & 31;
    const int z  = g >> 5;             // 0..1
    const int q0 = xq * 128;

    const int rowA = t >> 3, vA = t & 7;
    const int giA = (vA - rowA) & 7;
    const int rowB = rowA + 32;
    const int giB = (vA - rowB) & 7;

    const size_t kbase = (size_t)bh * SEQ * 64;   // Kb: [bh][n][d]
    const size_t vbase = (size_t)bh * 64 * SEQ;   // Vt: [bh][d][n]

    const uint4 ones_u = {0x3F803F80u, 0x3F803F80u, 0x3F803F80u, 0x3F803F80u};
    const bf16x8 onesf = __builtin_bit_cast(bf16x8, ones_u);

    bf16x8 aq[2][2];
#pragma unroll
    for (int mi = 0; mi < 2; ++mi)
#pragma unroll
        for (int ks = 0; ks < 2; ++ks)
            aq[mi][ks] = ld_frag(Qb + ((size_t)bh * SEQ + q0 + w * 32 + mi * 16 + l15) * 64
                                 + ks * 32 + quad * 8);

    // stage tile kt into buffer buf (swizzled dest cols, matching frag reads)
#define STAGE(kt_, buf_)                                                          \
    {                                                                             \
        const int k0_ = z * 1024 + (kt_) * 64;                                    \
        gld_lds16(Kb + kbase + (size_t)(k0_ + rowA) * 64 + giA * 8,               \
                  &Ks[buf_][t * 8]);                                              \
        gld_lds16(Kb + kbase + (size_t)(k0_ + rowB) * 64 + giB * 8,               \
                  &Ks[buf_][2048 + t * 8]);                                       \
        gld_lds16(Vt + vbase + (size_t)rowA * SEQ + k0_ + giA * 8,                \
                  &Vs[buf_][t * 8]);                                              \
        gld_lds16(Vt + vbase + (size_t)rowB * SEQ + k0_ + giB * 8,                \
                  &Vs[buf_][2048 + t * 8]);                                       \
    }

    STAGE(0, 0)

    f32x4 oacc[2][4] = {};
    f32x4 lacc[2] = {};

    int rb = 0;                              // buffer holding tile kt
    for (int kt = 0; kt < 16; ++kt) {
        const int sb = (rb + 1 == 3) ? 0 : rb + 1;
        if (kt + 1 < 16) {
            STAGE(kt + 1, sb)                // 4 loads stay in flight
            asm volatile("s_waitcnt vmcnt(4)" ::: "memory");
        } else {
            asm volatile("s_waitcnt vmcnt(0)" ::: "memory");
        }
        __builtin_amdgcn_sched_barrier(0);
        __builtin_amdgcn_s_barrier();        // raw barrier: no vmcnt drain
        __builtin_amdgcn_sched_barrier(0);
        const u16* ksm = Ks[rb];
        const u16* vsm = Vs[rb];

        // S^T = K Q^T : lane holds (q = l15, k = nk*16 + quad*4 + r)
        f32x4 sacc[2][4] = {};
        __builtin_amdgcn_s_setprio(1);
#pragma unroll
        for (int ks = 0; ks < 2; ++ks)
#pragma unroll
            for (int nk = 0; nk < 4; ++nk) {
                const int rK = nk * 16 + l15;
                const bf16x8 kf = ld_frag(ksm + (rK * 8 + (((ks * 4 + quad) + rK) & 7)) * 8);
                sacc[0][nk] = mfma16(kf, aq[0][ks], sacc[0][nk]);
                sacc[1][nk] = mfma16(kf, aq[1][ks], sacc[1][nk]);
            }
        __builtin_amdgcn_s_setprio(0);

        // softmax-lite + in-register repack to PV A-frags.
        bf16x8 pa[2][2];
#pragma unroll
        for (int mi = 0; mi < 2; ++mi) {
            u32 W[4][2];
#pragma unroll
            for (int nk = 0; nk < 4; ++nk) {
                const float p0 = fexp2(sacc[mi][nk][0]);
                const float p1 = fexp2(sacc[mi][nk][1]);
                const float p2 = fexp2(sacc[mi][nk][2]);
                const float p3 = fexp2(sacc[mi][nk][3]);
                W[nk][0] = pkbf(p0, p1);
                W[nk][1] = pkbf(p2, p3);
            }
            u32 t0[4], t1[4];
            {
                u32 a = W[0][0], cc = W[1][0];
                pl32swap(a, cc); pl16swap(a, cc);
                t0[0] = a; t0[2] = cc;
            }
            {
                u32 a = W[0][1], cc = W[1][1];
                pl32swap(a, cc); pl16swap(a, cc);
                t0[1] = a; t0[3] = cc;
            }
            {
                u32 a = W[2][0], cc = W[3][0];
                pl32swap(a, cc); pl16swap(a, cc);
                t1[0] = a; t1[2] = cc;
            }
            {
                u32 a = W[2][1], cc = W[3][1];
                pl32swap(a, cc); pl16swap(a, cc);
                t1[1] = a; t1[3] = cc;
            }
            uint4 u0; u0.x = t0[0]; u0.y = t0[1]; u0.z = t0[2]; u0.w = t0[3];
            uint4 u1; u1.x = t1[0]; u1.y = t1[1]; u1.z = t1[2]; u1.w = t1[3];
            pa[mi][0] = __builtin_bit_cast(bf16x8, u0);
            pa[mi][1] = __builtin_bit_cast(bf16x8, u1);
        }

        // O += P V ; l += P @ ones
        __builtin_amdgcn_s_setprio(1);
        lacc[0] = mfma16(pa[0][0], onesf, lacc[0]);
        lacc[0] = mfma16(pa[0][1], onesf, lacc[0]);
        lacc[1] = mfma16(pa[1][0], onesf, lacc[1]);
        lacc[1] = mfma16(pa[1][1], onesf, lacc[1]);
#pragma unroll
        for (int ks = 0; ks < 2; ++ks)
#pragma unroll
            for (int nj = 0; nj < 4; ++nj) {
                const int rV = nj * 16 + l15;
                const bf16x8 vf = ld_frag(vsm + (rV * 8 + (((ks * 4 + quad) + rV) & 7)) * 8);
                oacc[0][nj] = mfma16(pa[0][ks], vf, oacc[0][nj]);
                oacc[1][nj] = mfma16(pa[1][ks], vf, oacc[1][nj]);
            }
        __builtin_amdgcn_s_setprio(0);
        rb = sb;
    }
#undef STAGE

    // epilogue: lacc C-layout (row = quad*4+r, value replicated over cols)
    u16* ob = Opart + (size_t)z * 4194304;
#pragma unroll
    for (int mi = 0; mi < 2; ++mi)
#pragma unroll
        for (int r = 0; r < 4; ++r) {
            const int qrow = q0 + w * 32 + mi * 16 + quad * 4 + r;
            if (l15 == 0)
                lpart[((size_t)z * 32 + bh) * SEQ + qrow] = lacc[mi][r];
            const size_t orow = ((size_t)bh * SEQ + qrow) * 64;
#pragma unroll
            for (int nj = 0; nj < 4; ++nj)
                ob[orow + nj * 16 + l15] = f2bf(oacc[mi][nj][r]);
        }
}

// ---------------------------------------------------------------------------
// Merge the two K-splits: O = (O1 + O2) / (l1 + l2), repack to (B,N,H*DH) bf16.
// ---------------------------------------------------------------------------
__global__ __launch_bounds__(256) void merge_kernel(const u16* __restrict__ Opart,
                                                    const float* __restrict__ lpart,
                                                    u16* __restrict__ Ob) {
    const int gid = blockIdx.x * 256 + threadIdx.x;     // 1,048,576 total
    const int d4 = gid & 15, q = (gid >> 4) & 2047, bh = gid >> 15;
    const size_t i1 = ((size_t)bh * SEQ + q) * 64 + d4 * 4;
    const size_t i2 = i1 + 4194304;
    const float inv = 1.0f / (lpart[(size_t)bh * SEQ + q] +
                              lpart[((size_t)32 + bh) * SEQ + q]);
    const ushort4 a = *(const ushort4*)(Opart + i1);
    const ushort4 b = *(const ushort4*)(Opart + i2);
    ushort4 o;
    o.x = f2bf((bf2f(a.x) + bf2f(b.x)) * inv);
    o.y = f2bf((bf2f(a.y) + bf2f(b.y)) * inv);
    o.z = f2bf((bf2f(a.z) + bf2f(b.z)) * inv);
    o.w = f2bf((bf2f(a.w) + bf2f(b.w)) * inv);
    const int b_ = bh >> 4, h = bh & 15;
    *(ushort4*)(Ob + ((size_t)(b_ * SEQ + q)) * CH + h * 64 + d4 * 4) = o;
}

// ---------------------------------------------------------------------------
// Proj GEMM: 64x128 tile (grid 8 x 64 = 512 blocks = 2/CU), double-buffered,
// direct fp32 stores + bias. Wave (wm,wn): rows [wm*32,+32), cols [wn*64,+64);
// acc[2][4]. 8 MFMA + 6 frag-loads per k-iter.
// ---------------------------------------------------------------------------
__global__ __launch_bounds__(256) void gemm_proj(const u16* __restrict__ A,
                                                 const u16* __restrict__ Bw,
                                                 const float* __restrict__ bias,
                                                 float* __restrict__ C) {
    __shared__ u16 smem[12288];   // As dbuf 2x2048 u16; Bs dbuf 2x4096 u16
    const int t = threadIdx.x, lane = t & 63, w = t >> 6;
    const int l15 = lane & 15, quad = lane >> 4;
    const int wm = w >> 1, wn = w & 1;
    const int m0 = blockIdx.y * 64, n0 = blockIdx.x * 128;
    const int K = CH, N = CH;

    const int row0 = t >> 2, v0 = t & 3;              // A rows 0..63, B rows 0..63
    const int gi0 = (v0 - (row0 >> 1)) & 3;
    const int row1 = row0 + 64;                       // B rows 64..127
    const int gi1 = (v0 - (row1 >> 1)) & 3;

    const u16* A0 = A  + (size_t)(m0 + row0) * K + gi0 * 8;
    const u16* B0 = Bw + (size_t)(n0 + row0) * K + gi0 * 8;
    const u16* B1 = Bw + (size_t)(n0 + row1) * K + gi1 * 8;

    // buffers (u16 offsets): As: buf*2048; Bs base 4096: buf*4096
    gld_lds16(A0, smem + t * 8);
    gld_lds16(B0, smem + 4096 + t * 8);
    gld_lds16(B1, smem + 4096 + 2048 + t * 8);

    f32x4 acc[2][4] = {};
    for (int kt = 0; kt < K / 32; ++kt) {
        __syncthreads();
        const int curA = (kt & 1) * 2048;
        const int curB = 4096 + (kt & 1) * 4096;
        if (kt + 1 < K / 32) {
            const int off = (kt + 1) * 32;
            const int nxtA = ((kt + 1) & 1) * 2048;
            const int nxtB = 4096 + ((kt + 1) & 1) * 4096;
            gld_lds16(A0 + off, smem + nxtA + t * 8);
            gld_lds16(B0 + off, smem + nxtB + t * 8);
            gld_lds16(B1 + off, smem + nxtB + 2048 + t * 8);
        }
        const u16* as = smem + curA;
        const u16* bs = smem + curB;
        bf16x8 af[2], bfv[4];
#pragma unroll
        for (int mi = 0; mi < 2; ++mi) {
            const int r = wm * 32 + mi * 16 + l15;    // 0..63
            af[mi] = ld_frag(as + (r * 4 + ((quad + (r >> 1)) & 3)) * 8);
        }
#pragma unroll
        for (int nj = 0; nj < 4; ++nj) {
            const int r = wn * 64 + nj * 16 + l15;    // 0..127
            bfv[nj] = ld_frag(bs + (r * 4 + ((quad + (r >> 1)) & 3)) * 8);
        }
#pragma unroll
        for (int mi = 0; mi < 2; ++mi)
#pragma unroll
            for (int nj = 0; nj < 4; ++nj)
                acc[mi][nj] = mfma16(af[mi], bfv[nj], acc[mi][nj]);
    }
#pragma unroll
    for (int mi = 0; mi < 2; ++mi)
#pragma unroll
        for (int nj = 0; nj < 4; ++nj) {
            const int n = n0 + wn * 64 + nj * 16 + l15;
            const float bv = bias[n];
#pragma unroll
            for (int r = 0; r < 4; ++r) {
                const int m = m0 + wm * 32 + mi * 16 + quad * 4 + r;
                C[(size_t)m * N + n] = acc[mi][nj][r] + bv;
            }
        }
}

// ---------------------------------------------------------------------------
// Workspace layout (u16 offsets; extent 29,360,128 u16 = 56.00 MiB, proven):
//   [0         ..  4,194,304)  x_bf      -> attn_bf after qkv (merge out)
//   [4,194,304 ..  7,340,032)  wq_bf     -> lpart after qkv   (attn out)
//   [7,340,032 ..  8,388,608)  wp_bf     (live until proj)
//   [8,388,608 .. 12,582,912)  Qb
//   [12,582,912.. 16,777,216)  Kb
//   [16,777,216.. 20,971,520)  Vt
//   [20,971,520.. 29,360,128)  Opart (2 splits x 4.19M u16); first 16 KB
//                              doubles as tabq/tabk (dead before attn writes)
// ---------------------------------------------------------------------------
extern "C" void kernel_launch(void* const* d_in, const int* in_sizes, int n_in,
                              void* d_out, int out_size, void* d_ws, size_t ws_size,
                              hipStream_t stream) {
    const float* x      = (const float*)d_in[0];
    const int*   pos    = (const int*)d_in[1];
    const float* qkv_w  = (const float*)d_in[2];
    const float* proj_w = (const float*)d_in[3];
    const float* proj_b = (const float*)d_in[4];
    float* out = (float*)d_out;

    u16* ws = (u16*)d_ws;
    u16* x_bf    = ws;
    u16* attn_bf = ws;                          // aliases x_bf (dead after qkv)
    u16* wq_bf   = ws + 4194304;
    float* lpart = (float*)(ws + 4194304);      // aliases wq_bf (dead after qkv)
    u16* wp_bf   = ws + 7340032;
    u16* Qb      = ws + 8388608;
    u16* Kb      = ws + 12582912;
    u16* Vt      = ws + 16777216;
    u16* Opart   = ws + 20971520;
    float2* tabq = (float2*)(ws + 20971520);    // aliases Opart head (dead by attn)
    float2* tabk = (float2*)(ws + 20971520 + 4096);

    const int M = BB * SEQ;  // 4096

    convert_kernel<<<8196, 256, 0, stream>>>(x, qkv_w, proj_w, x_bf, wq_bf, wp_bf,
                                             tabq, tabk);
    gemm_qkv_rope<<<dim3(3 * CH / 128, M / 128), 256, 0, stream>>>(
        x_bf, wq_bf, pos, tabq, tabk, Qb, Kb, Vt);
    attn_mfma<<<1024, 256, 0, stream>>>(Qb, Kb, Vt, Opart, lpart);
    merge_kernel<<<4096, 256, 0, stream>>>(Opart, lpart, attn_bf);
    gemm_proj<<<dim3(CH / 128, M / 64), 256, 0, stream>>>(
        attn_bf, wp_bf, proj_b, out);
}

// Round 6
// 194.265 us; speedup vs baseline: 1.3648x; 1.0265x over previous
//
#include <hip/hip_runtime.h>
#include <cmath>

typedef unsigned short u16;
typedef unsigned int   u32;
typedef __attribute__((ext_vector_type(8))) __bf16 bf16x8;
typedef __attribute__((ext_vector_type(2))) __bf16 bf16x2;
typedef __attribute__((ext_vector_type(4))) float  f32x4;
typedef __attribute__((ext_vector_type(2))) unsigned int u32x2;

constexpr int BB = 2, SEQ = 2048, CH = 1024, NH = 16, DH = 64;

__device__ inline u16 f2bf(float f) {            // RNE fp32 -> bf16
    u32 u = __builtin_bit_cast(u32, f);
    u += 0x7FFF + ((u >> 16) & 1);
    return (u16)(u >> 16);
}
__device__ inline float bf2f(u16 b) { return __builtin_bit_cast(float, (u32)b << 16); }
__device__ inline u32 pkbf(float a, float b) {   // pack two RNE bf16 into u32
#if __has_builtin(__builtin_amdgcn_cvt_pk_bf16_f32)
    bf16x2 r = __builtin_amdgcn_cvt_pk_bf16_f32(a, b);
    return __builtin_bit_cast(u32, r);
#else
    return (u32)f2bf(a) | ((u32)f2bf(b) << 16);
#endif
}
__device__ inline float fexp2(float x) {
#if __has_builtin(__builtin_amdgcn_exp2f)
    return __builtin_amdgcn_exp2f(x);
#else
    return exp2f(x);
#endif
}

// permlane swaps (gfx950). P32: a'=[a0,a1,b0,b1] b'=[a2,a3,b2,b3] (16-lane rows)
// P16: a'=[a0,b0,a2,b2] b'=[a1,b1,a3,b3]
__device__ inline void pl32swap(u32& a, u32& b) {
#if __has_builtin(__builtin_amdgcn_permlane32_swap)
    u32x2 r = __builtin_amdgcn_permlane32_swap(a, b, false, false);
    a = r.x; b = r.y;
#else
    const int ln = threadIdx.x & 63;
    u32 ax = (u32)__shfl_xor((int)a, 32), bx = (u32)__shfl_xor((int)b, 32);
    u32 na = (ln & 32) ? bx : a;
    u32 nb = (ln & 32) ? b : ax;
    a = na; b = nb;
#endif
}
__device__ inline void pl16swap(u32& a, u32& b) {
#if __has_builtin(__builtin_amdgcn_permlane16_swap)
    u32x2 r = __builtin_amdgcn_permlane16_swap(a, b, false, false);
    a = r.x; b = r.y;
#else
    const int ln = threadIdx.x & 63;
    u32 ax = (u32)__shfl_xor((int)a, 16), bx = (u32)__shfl_xor((int)b, 16);
    u32 na = (ln & 16) ? bx : a;
    u32 nb = (ln & 16) ? b : ax;
    a = na; b = nb;
#endif
}

__device__ inline void gld_lds16(const void* g, void* l) {
    __builtin_amdgcn_global_load_lds((const __attribute__((address_space(1))) void*)g,
                                     (__attribute__((address_space(3))) void*)l, 16, 0, 0);
}
__device__ inline f32x4 mfma16(bf16x8 a, bf16x8 b, f32x4 c) {
    return __builtin_amdgcn_mfma_f32_16x16x32_bf16(a, b, c, 0, 0, 0);
}
__device__ inline bf16x8 ld_frag(const u16* p) {
    return __builtin_bit_cast(bf16x8, *(const uint4*)p);
}

// ---------------------------------------------------------------------------
// fp32 -> bf16 conversion for x, qkv_w, proj_w + RoPE sin/cos table gen.
// ---------------------------------------------------------------------------
__global__ __launch_bounds__(256) void convert_kernel(const float* __restrict__ x,
                                                      const float* __restrict__ wq,
                                                      const float* __restrict__ wp,
                                                      u16* __restrict__ xb,
                                                      u16* __restrict__ wqb,
                                                      u16* __restrict__ wpb,
                                                      float2* __restrict__ tabq,
                                                      float2* __restrict__ tabk) {
    const int q = blockIdx.x * 256 + threadIdx.x;   // quad index
    if (q >= 2097152) {                             // table-gen tail: 1024 threads
        const int idx = q - 2097152;
        if (idx < 1024) {
            const int p = idx >> 4, i = idx & 15;
            const float f = exp2f(-(float)i * 0.41524101186092f);  // log2(100)/16
            float s, c;
            sincosf((float)p * f, &s, &c);
            tabk[idx] = make_float2(c, s);
            tabq[idx] = make_float2(c * 0.18033688011112042f,
                                    s * 0.18033688011112042f);
        }
        return;
    }
    const float* src; u16* dst; int idx;
    if (q < 1048576)            { src = x;  dst = xb;  idx = q; }
    else if (q < 1048576+786432){ src = wq; dst = wqb; idx = q - 1048576; }
    else                        { src = wp; dst = wpb; idx = q - 1048576 - 786432; }
    float4 v = *(const float4*)(src + (size_t)idx * 4);
    ushort4 o; o.x = f2bf(v.x); o.y = f2bf(v.y); o.z = f2bf(v.z); o.w = f2bf(v.w);
    *(ushort4*)(dst + (size_t)idx * 4) = o;
}

// ---------------------------------------------------------------------------
// Fused QKV GEMM + RoPE + head-major repack, double-buffered staging,
// LDS-transpose epilogue (all three outputs written as coalesced 16B chunks).
// ---------------------------------------------------------------------------
__global__ __launch_bounds__(256) void gemm_qkv_rope(const u16* __restrict__ A,
                                                     const u16* __restrict__ Bw,
                                                     const int* __restrict__ pos,
                                                     const float2* __restrict__ tabq,
                                                     const float2* __restrict__ tabk,
                                                     u16* __restrict__ Qb,
                                                     u16* __restrict__ Kb,
                                                     u16* __restrict__ Vt) {
    __shared__ u16 smem[18432];   // dbuf staging [0,16384); epilogue T = 4 x 4608
    const int t = threadIdx.x, lane = t & 63, w = t >> 6;
    const int l15 = lane & 15, quad = lane >> 4;
    const int wm = w >> 1, wn = w & 1;
    const int m0 = blockIdx.y * 128, n0 = blockIdx.x * 128;
    const int K = CH;

    const int row0 = t >> 2, v0 = t & 3;
    const int gi0 = (v0 - (row0 >> 1)) & 3;
    const int row1 = row0 + 64;
    const int gi1 = (v0 - (row1 >> 1)) & 3;

    const u16* A0 = A  + (size_t)(m0 + row0) * K + gi0 * 8;
    const u16* A1 = A  + (size_t)(m0 + row1) * K + gi1 * 8;
    const u16* B0 = Bw + (size_t)(n0 + row0) * K + gi0 * 8;
    const u16* B1 = Bw + (size_t)(n0 + row1) * K + gi1 * 8;

    gld_lds16(A0, smem + t * 8);
    gld_lds16(A1, smem + 2048 + t * 8);
    gld_lds16(B0, smem + 8192 + t * 8);
    gld_lds16(B1, smem + 10240 + t * 8);

    f32x4 acc[4][4] = {};
    for (int kt = 0; kt < K / 32; ++kt) {
        __syncthreads();          // drains own prefetch (vmcnt 0) + block sync
        const int cur = (kt & 1) * 4096;
        if (kt + 1 < K / 32) {
            const int off = (kt + 1) * 32;
            const int nxt = ((kt + 1) & 1) * 4096;
            gld_lds16(A0 + off, smem + nxt + t * 8);
            gld_lds16(A1 + off, smem + nxt + 2048 + t * 8);
            gld_lds16(B0 + off, smem + 8192 + nxt + t * 8);
            gld_lds16(B1 + off, smem + 8192 + nxt + 2048 + t * 8);
        }
        const u16* as = smem + cur;
        const u16* bs = smem + 8192 + cur;
        bf16x8 af[4], bfv[4];
#pragma unroll
        for (int mi = 0; mi < 4; ++mi) {
            const int r = wm * 64 + mi * 16 + l15;
            af[mi] = ld_frag(as + (r * 4 + ((quad + (r >> 1)) & 3)) * 8);
        }
#pragma unroll
        for (int nj = 0; nj < 4; ++nj) {
            const int r = wn * 64 + nj * 16 + l15;
            bfv[nj] = ld_frag(bs + (r * 4 + ((quad + (r >> 1)) & 3)) * 8);
        }
#pragma unroll
        for (int mi = 0; mi < 4; ++mi)
#pragma unroll
            for (int nj = 0; nj < 4; ++nj)
                acc[mi][nj] = mfma16(af[mi], bfv[nj], acc[mi][nj]);
    }

    const int reg = n0 >> 10;                      // 0=q, 1=k, 2=v (block-uniform)
    const int h   = ((n0 & 1023) >> 6) + wn;       // wave's head
    __syncthreads();                               // staging fully consumed
    u16* T = smem + w * 4608;                      // 64 rows x stride 72 u16
    const int rsel = lane >> 3, csel = lane & 7;   // out mapping: 8 lanes/row
    if (reg < 2) {
        const float2* tab = reg ? tabk : tabq;     // scale folded into tabq
        u16* dstb = reg ? Kb : Qb;
#pragma unroll
        for (int mi = 0; mi < 4; ++mi) {
#pragma unroll
            for (int r = 0; r < 4; ++r) {
                const int m = m0 + wm * 64 + mi * 16 + quad * 4 + r;  // b*SEQ+n
                const int2 pp = *(const int2*)(pos + m * 2);
                const float2 ty = tab[pp.x * 16 + l15];
                const float2 tx = tab[pp.y * 16 + l15];
                const float x1 = acc[mi][0][r], x2 = acc[mi][1][r];
                const float y1 = acc[mi][2][r], y2 = acc[mi][3][r];
                const int ml = (mi * 16 + quad * 4 + r) * 72;
                T[ml + l15]      = f2bf(x1 * ty.x - x2 * ty.y);
                T[ml + l15 + 16] = f2bf(x1 * ty.y + x2 * ty.x);
                T[ml + l15 + 32] = f2bf(y1 * tx.x - y2 * tx.y);
                T[ml + l15 + 48] = f2bf(y1 * tx.y + y2 * tx.x);
            }
        }
        // same-wave LDS RAW (DS in-order per wave): read rows, 1KB/inst stores
        const int mbase = m0 + wm * 64;
        const int bh = (mbase >> 11) * NH + h;
        const int nbase = mbase & 2047;
#pragma unroll
        for (int j = 0; j < 8; ++j) {
            const int row = rsel + j * 8;
            u16* gp = dstb + ((size_t)bh * SEQ + nbase + row) * 64 + csel * 8;
            *(uint4*)gp = *(const uint4*)&T[row * 72 + csel * 8];
        }
    } else {
        // V: transpose 64x64 (rows = head-dim d) -> Vt[bh][d][n]
#pragma unroll
        for (int mi = 0; mi < 4; ++mi)
#pragma unroll
            for (int nj = 0; nj < 4; ++nj)
#pragma unroll
                for (int r = 0; r < 4; ++r)
                    T[(nj * 16 + l15) * 72 + mi * 16 + quad * 4 + r] =
                        f2bf(acc[mi][nj][r]);
        const int bh = (m0 >> 11) * NH + h;
        const int nbase = (m0 & 2047) + wm * 64;
#pragma unroll
        for (int j = 0; j < 8; ++j) {
            const int d = rsel + j * 8;
            u16* gp = Vt + ((size_t)bh * 64 + d) * SEQ + nbase + csel * 8;
            *(uint4*)gp = *(const uint4*)&T[d * 72 + csel * 8];
        }
    }
}

// ---------------------------------------------------------------------------
// Flash attention: bf16 MFMA, softmax-lite (exp2 only, no max), NO split-K
// (R13): R0-R12 proved attn dur invariant to occupancy 22-50% — split-K
// bought nothing and cost Opart 34MB round-trip + merge dispatch. One pass
// over all 32 k-tiles; epilogue normalizes by lacc (replicated across l15
// in C-layout) and writes bf16 directly to attn_bf in (B,N,C) layout.
// R12 triple-buffer counted-vmcnt loop retained. XCD decode: 4 heads/XCD.
// ---------------------------------------------------------------------------
__global__ __launch_bounds__(256, 3) void attn_mfma(const u16* __restrict__ Qb,
                                                    const u16* __restrict__ Kb,
                                                    const u16* __restrict__ Vt,
                                                    u16* __restrict__ Ob) {
    __shared__ u16 Ks[3][4096];
    __shared__ u16 Vs[3][4096];
    const int t = threadIdx.x, lane = t & 63, w = t >> 6;
    const int l15 = lane & 15, quad = lane >> 4;

    // XCD-grouped decode: 512 blocks; XCD c gets heads {c, c+8, c+16, c+24}.
    const int id = blockIdx.x;
    const int c  = id & 7, r_ = id >> 3;
    const int j  = r_ >> 4, xq = r_ & 15;
    const int bh = c + 8 * j;          // 0..31
    const int q0 = xq * 128;

    const int rowA = t >> 3, vA = t & 7;
    const int giA = (vA - rowA) & 7;
    const int rowB = rowA + 32;
    const int giB = (vA - rowB) & 7;

    const size_t kbase = (size_t)bh * SEQ * 64;   // Kb: [bh][n][d]
    const size_t vbase = (size_t)bh * 64 * SEQ;   // Vt: [bh][d][n]

    const uint4 ones_u = {0x3F803F80u, 0x3F803F80u, 0x3F803F80u, 0x3F803F80u};
    const bf16x8 onesf = __builtin_bit_cast(bf16x8, ones_u);

    bf16x8 aq[2][2];
#pragma unroll
    for (int mi = 0; mi < 2; ++mi)
#pragma unroll
        for (int ks = 0; ks < 2; ++ks)
            aq[mi][ks] = ld_frag(Qb + ((size_t)bh * SEQ + q0 + w * 32 + mi * 16 + l15) * 64
                                 + ks * 32 + quad * 8);

    // stage tile kt into buffer buf (swizzled dest cols, matching frag reads)
#define STAGE(kt_, buf_)                                                          \
    {                                                                             \
        const int k0_ = (kt_) * 64;                                               \
        gld_lds16(Kb + kbase + (size_t)(k0_ + rowA) * 64 + giA * 8,               \
                  &Ks[buf_][t * 8]);                                              \
        gld_lds16(Kb + kbase + (size_t)(k0_ + rowB) * 64 + giB * 8,               \
                  &Ks[buf_][2048 + t * 8]);                                       \
        gld_lds16(Vt + vbase + (size_t)rowA * SEQ + k0_ + giA * 8,                \
                  &Vs[buf_][t * 8]);                                              \
        gld_lds16(Vt + vbase + (size_t)rowB * SEQ + k0_ + giB * 8,                \
                  &Vs[buf_][2048 + t * 8]);                                       \
    }

    STAGE(0, 0)

    f32x4 oacc[2][4] = {};
    f32x4 lacc[2] = {};

    int rb = 0;                              // buffer holding tile kt
    for (int kt = 0; kt < 32; ++kt) {
        const int sb = (rb + 1 == 3) ? 0 : rb + 1;
        if (kt + 1 < 32) {
            STAGE(kt + 1, sb)                // 4 loads stay in flight
            asm volatile("s_waitcnt vmcnt(4)" ::: "memory");
        } else {
            asm volatile("s_waitcnt vmcnt(0)" ::: "memory");
        }
        __builtin_amdgcn_sched_barrier(0);
        __builtin_amdgcn_s_barrier();        // raw barrier: no vmcnt drain
        __builtin_amdgcn_sched_barrier(0);
        const u16* ksm = Ks[rb];
        const u16* vsm = Vs[rb];

        // S^T = K Q^T : lane holds (q = l15, k = nk*16 + quad*4 + r)
        f32x4 sacc[2][4] = {};
        __builtin_amdgcn_s_setprio(1);
#pragma unroll
        for (int ks = 0; ks < 2; ++ks)
#pragma unroll
            for (int nk = 0; nk < 4; ++nk) {
                const int rK = nk * 16 + l15;
                const bf16x8 kf = ld_frag(ksm + (rK * 8 + (((ks * 4 + quad) + rK) & 7)) * 8);
                sacc[0][nk] = mfma16(kf, aq[0][ks], sacc[0][nk]);
                sacc[1][nk] = mfma16(kf, aq[1][ks], sacc[1][nk]);
            }
        __builtin_amdgcn_s_setprio(0);

        // softmax-lite + in-register repack to PV A-frags.
        bf16x8 pa[2][2];
#pragma unroll
        for (int mi = 0; mi < 2; ++mi) {
            u32 W[4][2];
#pragma unroll
            for (int nk = 0; nk < 4; ++nk) {
                const float p0 = fexp2(sacc[mi][nk][0]);
                const float p1 = fexp2(sacc[mi][nk][1]);
                const float p2 = fexp2(sacc[mi][nk][2]);
                const float p3 = fexp2(sacc[mi][nk][3]);
                W[nk][0] = pkbf(p0, p1);
                W[nk][1] = pkbf(p2, p3);
            }
            u32 t0[4], t1[4];
            {
                u32 a = W[0][0], cc = W[1][0];
                pl32swap(a, cc); pl16swap(a, cc);
                t0[0] = a; t0[2] = cc;
            }
            {
                u32 a = W[0][1], cc = W[1][1];
                pl32swap(a, cc); pl16swap(a, cc);
                t0[1] = a; t0[3] = cc;
            }
            {
                u32 a = W[2][0], cc = W[3][0];
                pl32swap(a, cc); pl16swap(a, cc);
                t1[0] = a; t1[2] = cc;
            }
            {
                u32 a = W[2][1], cc = W[3][1];
                pl32swap(a, cc); pl16swap(a, cc);
                t1[1] = a; t1[3] = cc;
            }
            uint4 u0; u0.x = t0[0]; u0.y = t0[1]; u0.z = t0[2]; u0.w = t0[3];
            uint4 u1; u1.x = t1[0]; u1.y = t1[1]; u1.z = t1[2]; u1.w = t1[3];
            pa[mi][0] = __builtin_bit_cast(bf16x8, u0);
            pa[mi][1] = __builtin_bit_cast(bf16x8, u1);
        }

        // O += P V ; l += P @ ones
        __builtin_amdgcn_s_setprio(1);
        lacc[0] = mfma16(pa[0][0], onesf, lacc[0]);
        lacc[0] = mfma16(pa[0][1], onesf, lacc[0]);
        lacc[1] = mfma16(pa[1][0], onesf, lacc[1]);
        lacc[1] = mfma16(pa[1][1], onesf, lacc[1]);
#pragma unroll
        for (int ks = 0; ks < 2; ++ks)
#pragma unroll
            for (int nj = 0; nj < 4; ++nj) {
                const int rV = nj * 16 + l15;
                const bf16x8 vf = ld_frag(vsm + (rV * 8 + (((ks * 4 + quad) + rV) & 7)) * 8);
                oacc[0][nj] = mfma16(pa[0][ks], vf, oacc[0][nj]);
                oacc[1][nj] = mfma16(pa[1][ks], vf, oacc[1][nj]);
            }
        __builtin_amdgcn_s_setprio(0);
        rb = sb;
    }
#undef STAGE

    // epilogue: normalize by l (lacc value replicated across l15 lanes) and
    // write bf16 to attn_bf in (B, N, H*DH) layout for gemm_proj.
    const int b_ = bh >> 4, h = bh & 15;
#pragma unroll
    for (int mi = 0; mi < 2; ++mi)
#pragma unroll
        for (int r = 0; r < 4; ++r) {
            const int qrow = q0 + w * 32 + mi * 16 + quad * 4 + r;
            const float inv = 1.0f / lacc[mi][r];
            u16* gp = Ob + ((size_t)(b_ * SEQ + qrow)) * CH + h * 64;
#pragma unroll
            for (int nj = 0; nj < 4; ++nj)
                gp[nj * 16 + l15] = f2bf(oacc[mi][nj][r] * inv);
        }
}

// ---------------------------------------------------------------------------
// Proj GEMM: 64x128 tile (grid 8 x 64 = 512 blocks = 2/CU), double-buffered,
// direct fp32 stores + bias. Wave (wm,wn): rows [wm*32,+32), cols [wn*64,+64);
// acc[2][4]. 8 MFMA + 6 frag-loads per k-iter.
// ---------------------------------------------------------------------------
__global__ __launch_bounds__(256) void gemm_proj(const u16* __restrict__ A,
                                                 const u16* __restrict__ Bw,
                                                 const float* __restrict__ bias,
                                                 float* __restrict__ C) {
    __shared__ u16 smem[12288];   // As dbuf 2x2048 u16; Bs dbuf 2x4096 u16
    const int t = threadIdx.x, lane = t & 63, w = t >> 6;
    const int l15 = lane & 15, quad = lane >> 4;
    const int wm = w >> 1, wn = w & 1;
    const int m0 = blockIdx.y * 64, n0 = blockIdx.x * 128;
    const int K = CH, N = CH;

    const int row0 = t >> 2, v0 = t & 3;              // A rows 0..63, B rows 0..63
    const int gi0 = (v0 - (row0 >> 1)) & 3;
    const int row1 = row0 + 64;                       // B rows 64..127
    const int gi1 = (v0 - (row1 >> 1)) & 3;

    const u16* A0 = A  + (size_t)(m0 + row0) * K + gi0 * 8;
    const u16* B0 = Bw + (size_t)(n0 + row0) * K + gi0 * 8;
    const u16* B1 = Bw + (size_t)(n0 + row1) * K + gi1 * 8;

    // buffers (u16 offsets): As: buf*2048; Bs base 4096: buf*4096
    gld_lds16(A0, smem + t * 8);
    gld_lds16(B0, smem + 4096 + t * 8);
    gld_lds16(B1, smem + 4096 + 2048 + t * 8);

    f32x4 acc[2][4] = {};
    for (int kt = 0; kt < K / 32; ++kt) {
        __syncthreads();
        const int curA = (kt & 1) * 2048;
        const int curB = 4096 + (kt & 1) * 4096;
        if (kt + 1 < K / 32) {
            const int off = (kt + 1) * 32;
            const int nxtA = ((kt + 1) & 1) * 2048;
            const int nxtB = 4096 + ((kt + 1) & 1) * 4096;
            gld_lds16(A0 + off, smem + nxtA + t * 8);
            gld_lds16(B0 + off, smem + nxtB + t * 8);
            gld_lds16(B1 + off, smem + nxtB + 2048 + t * 8);
        }
        const u16* as = smem + curA;
        const u16* bs = smem + curB;
        bf16x8 af[2], bfv[4];
#pragma unroll
        for (int mi = 0; mi < 2; ++mi) {
            const int r = wm * 32 + mi * 16 + l15;    // 0..63
            af[mi] = ld_frag(as + (r * 4 + ((quad + (r >> 1)) & 3)) * 8);
        }
#pragma unroll
        for (int nj = 0; nj < 4; ++nj) {
            const int r = wn * 64 + nj * 16 + l15;    // 0..127
            bfv[nj] = ld_frag(bs + (r * 4 + ((quad + (r >> 1)) & 3)) * 8);
        }
#pragma unroll
        for (int mi = 0; mi < 2; ++mi)
#pragma unroll
            for (int nj = 0; nj < 4; ++nj)
                acc[mi][nj] = mfma16(af[mi], bfv[nj], acc[mi][nj]);
    }
#pragma unroll
    for (int mi = 0; mi < 2; ++mi)
#pragma unroll
        for (int nj = 0; nj < 4; ++nj) {
            const int n = n0 + wn * 64 + nj * 16 + l15;
            const float bv = bias[n];
#pragma unroll
            for (int r = 0; r < 4; ++r) {
                const int m = m0 + wm * 32 + mi * 16 + quad * 4 + r;
                C[(size_t)m * N + n] = acc[mi][nj][r] + bv;
            }
        }
}

// ---------------------------------------------------------------------------
// Workspace layout (u16 offsets; extent 29,360,128 u16 = 56.00 MiB, proven):
//   [0         ..  4,194,304)  x_bf      -> attn_bf after qkv (attn out)
//   [4,194,304 ..  7,340,032)  wq_bf     (dead after qkv)
//   [7,340,032 ..  8,388,608)  wp_bf     (live until proj)
//   [8,388,608 .. 12,582,912)  Qb
//   [12,582,912.. 16,777,216)  Kb
//   [16,777,216.. 20,971,520)  Vt
//   [20,971,520.. 20,987,904)  tabq/tabk (16 KB)
// ---------------------------------------------------------------------------
extern "C" void kernel_launch(void* const* d_in, const int* in_sizes, int n_in,
                              void* d_out, int out_size, void* d_ws, size_t ws_size,
                              hipStream_t stream) {
    const float* x      = (const float*)d_in[0];
    const int*   pos    = (const int*)d_in[1];
    const float* qkv_w  = (const float*)d_in[2];
    const float* proj_w = (const float*)d_in[3];
    const float* proj_b = (const float*)d_in[4];
    float* out = (float*)d_out;

    u16* ws = (u16*)d_ws;
    u16* x_bf    = ws;
    u16* attn_bf = ws;                          // aliases x_bf (dead after qkv)
    u16* wq_bf   = ws + 4194304;
    u16* wp_bf   = ws + 7340032;
    u16* Qb      = ws + 8388608;
    u16* Kb      = ws + 12582912;
    u16* Vt      = ws + 16777216;
    float2* tabq = (float2*)(ws + 20971520);
    float2* tabk = (float2*)(ws + 20971520 + 4096);

    const int M = BB * SEQ;  // 4096

    convert_kernel<<<8196, 256, 0, stream>>>(x, qkv_w, proj_w, x_bf, wq_bf, wp_bf,
                                             tabq, tabk);
    gemm_qkv_rope<<<dim3(3 * CH / 128, M / 128), 256, 0, stream>>>(
        x_bf, wq_bf, pos, tabq, tabk, Qb, Kb, Vt);
    attn_mfma<<<512, 256, 0, stream>>>(Qb, Kb, Vt, attn_bf);
    gemm_proj<<<dim3(CH / 128, M / 64), 256, 0, stream>>>(
        attn_bf, wp_bf, proj_b, out);
}